// Round 1
// baseline (748.114 us; speedup 1.0000x reference)
//
#include <hip/hip_runtime.h>
#include <cstdint>
#include <cstddef>

// Problem: B=1, L=2048, DIM=512, H=8, D=64, STEPS=1024, CHUNK irrelevant (full LxL).
//
// Pipeline (all fp32, exact table semantics):
//  K1 gemm_qs : qs = x @ W_qs + b_qs                      (2048x512 @ 512x1024)
//  K2 ln_act  : LayerNorm(1024) -> amp=sigmoid/L2norm, phase=tanh*pi
//               writes amp[h][i][d], pA[h][i][d] = qp*c1 + s2 + 1024, pB[h][i][d] = qp*c1
//               where c1 = f*1024/2pi, s2 = s*1024/2pi.  (+1024 folds numpy float-mod:
//               idx = (uint)(pA_i - pB_j) & 1023 reproduces mod semantics since |t|<1024)
//  K3 transpose: amp,pB -> [h][d][i] copies (coalesced + conflict-free k-staging in K4)
//  K4 flash   : per (head, 32-q tile): loop 64-k tiles: scores via LDS table gather,
//               p = exp(s/8) (no max needed, |s/8|<=0.02), online den/PV accumulate.
//  K5 out_gemm: out = att @ W_out + b_out
//
// ws layout (floats): [0,2M) qs (att reuses [0,1M) after qs is dead)
//                     [2M,3M) amp  [3M,4M) pA  [4M,5M) pB
//                     [5M,6M) ampT [6M,7M) pBT            -> needs 28 MB ws.

static constexpr size_t OFF_QS   = 0;
static constexpr size_t OFF_ATT  = 0;                    // reuse qs region
static constexpr size_t OFF_AMP  = (size_t)2 * 1024 * 1024;
static constexpr size_t OFF_PA   = (size_t)3 * 1024 * 1024;
static constexpr size_t OFF_PB   = (size_t)4 * 1024 * 1024;
static constexpr size_t OFF_AMPT = (size_t)5 * 1024 * 1024;
static constexpr size_t OFF_PBT  = (size_t)6 * 1024 * 1024;

// ---------------- K1: qs = x @ W_qs + b_qs ----------------
__global__ __launch_bounds__(256) void k_gemm_qs(const float* __restrict__ x,
                                                 const float* __restrict__ Wq,
                                                 const float* __restrict__ bq,
                                                 float* __restrict__ qs) {
  __shared__ float xs[8 * 512];
  const int r0 = blockIdx.x * 8;
  const int t = threadIdx.x;
  #pragma unroll
  for (int it = 0; it < 16; ++it) {
    int n = t + 256 * it;
    xs[n] = x[(size_t)r0 * 512 + n];
  }
  __syncthreads();
  float acc[8][4];
  #pragma unroll
  for (int c = 0; c < 4; ++c) {
    float bv = bq[t + 256 * c];
    #pragma unroll
    for (int r = 0; r < 8; ++r) acc[r][c] = bv;
  }
  for (int k = 0; k < 512; ++k) {
    const float* wrow = Wq + (size_t)k * 1024 + t;
    float w0 = wrow[0], w1 = wrow[256], w2 = wrow[512], w3 = wrow[768];
    #pragma unroll
    for (int r = 0; r < 8; ++r) {
      float xv = xs[r * 512 + k];
      acc[r][0] = fmaf(xv, w0, acc[r][0]);
      acc[r][1] = fmaf(xv, w1, acc[r][1]);
      acc[r][2] = fmaf(xv, w2, acc[r][2]);
      acc[r][3] = fmaf(xv, w3, acc[r][3]);
    }
  }
  #pragma unroll
  for (int r = 0; r < 8; ++r) {
    #pragma unroll
    for (int c = 0; c < 4; ++c)
      qs[(size_t)(r0 + r) * 1024 + t + 256 * c] = acc[r][c];
  }
}

// ---------------- K2: LayerNorm + activations + derived phase arrays ----------------
__global__ __launch_bounds__(256) void k_ln_act(const float* __restrict__ qs,
    const float* __restrict__ lnw, const float* __restrict__ lnb,
    const float* __restrict__ fr, const float* __restrict__ psh,
    float* __restrict__ amp, float* __restrict__ pA, float* __restrict__ pB) {
  __shared__ float red[256];
  __shared__ float red2[256];
  const int i = blockIdx.x, t = threadIdx.x;
  const float* row = qs + (size_t)i * 1024;
  float v0 = row[t], v1 = row[t + 256], v2 = row[t + 512], v3 = row[t + 768];
  red[t]  = v0 + v1 + v2 + v3;
  red2[t] = v0 * v0 + v1 * v1 + v2 * v2 + v3 * v3;
  __syncthreads();
  for (int st = 128; st > 0; st >>= 1) {
    if (t < st) { red[t] += red[t + st]; red2[t] += red2[t + st]; }
    __syncthreads();
  }
  float mu  = red[0] * (1.0f / 1024.0f);
  float var = red2[0] * (1.0f / 1024.0f) - mu * mu;
  float rstd = 1.0f / sqrtf(var + 1e-5f);
  float y0 = (v0 - mu) * rstd * lnw[t]       + lnb[t];
  float y1 = (v1 - mu) * rstd * lnw[t + 256] + lnb[t + 256];
  float y2 = (v2 - mu) * rstd * lnw[t + 512] + lnb[t + 512];
  float y3 = (v3 - mu) * rstd * lnw[t + 768] + lnb[t + 768];
  float a0 = 1.0f / (1.0f + expf(-y0));
  float a1 = 1.0f / (1.0f + expf(-y1));
  __syncthreads();                 // everyone done reading red[0]/red2[0]
  red[t] = a0 * a0 + a1 * a1;
  __syncthreads();
  for (int st = 128; st > 0; st >>= 1) {
    if (t < st) red[t] += red[t + st];
    __syncthreads();
  }
  float inv = 1.0f / (sqrtf(red[0]) + 1e-8f);
  float af0 = a0 * inv, af1 = a1 * inv;
  const float PI_F = 3.14159265358979323846f;
  float p2 = tanhf(y2) * PI_F;     // phase col t      -> head h0
  float p3 = tanhf(y3) * PI_F;     // phase col t+256  -> head h0+4
  const double k1024 = 1024.0 / 6.283185307179586;   // STEPS / TWO_PI
  int h0 = t >> 6, d0 = t & 63;
  int h1 = h0 + 4;
  float c10 = (float)((double)fr[h0] * k1024);
  float s20 = (float)((double)psh[h0] * k1024 + 1024.0);  // + 1024 folds the float mod
  float c11 = (float)((double)fr[h1] * k1024);
  float s21 = (float)((double)psh[h1] * k1024 + 1024.0);
  size_t base0 = (size_t)h0 * (2048 * 64) + (size_t)i * 64 + d0;
  size_t base1 = (size_t)h1 * (2048 * 64) + (size_t)i * 64 + d0;
  amp[base0] = af0;
  amp[base1] = af1;
  pA[base0] = fmaf(p2, c10, s20);
  pA[base1] = fmaf(p3, c11, s21);
  pB[base0] = p2 * c10;
  pB[base1] = p3 * c11;
}

// ---------------- K3: [h][i][d] -> [h][d][i] transpose for amp and pB ----------------
__global__ __launch_bounds__(256) void k_transpose(const float* __restrict__ amp,
    const float* __restrict__ pB, float* __restrict__ ampT, float* __restrict__ pBT) {
  const float* src = blockIdx.z ? pB : amp;
  float* dst       = blockIdx.z ? pBT : ampT;
  __shared__ float tl[64 * 65];
  const int h = blockIdx.y, i0 = blockIdx.x * 64, t = threadIdx.x;
  #pragma unroll
  for (int it = 0; it < 16; ++it) {
    int n = t + 256 * it;
    int ii = n >> 6, d = n & 63;
    tl[ii * 65 + d] = src[(size_t)h * (2048 * 64) + (size_t)(i0 + ii) * 64 + d];
  }
  __syncthreads();
  #pragma unroll
  for (int it = 0; it < 16; ++it) {
    int n = t + 256 * it;
    int d = n >> 6, ii = n & 63;
    dst[(size_t)h * (2048 * 64) + (size_t)d * 2048 + i0 + ii] = tl[ii * 65 + d];
  }
}

// ---------------- K4: fused interference-attention (flash-style) ----------------
__global__ __launch_bounds__(256, 2) void k_flash(const float* __restrict__ amp,
    const float* __restrict__ pA, const float* __restrict__ ampT,
    const float* __restrict__ pBT, const float* __restrict__ x,
    const float* __restrict__ tbl, float* __restrict__ att) {
  __shared__ float s_qa[64 * 34];   // [d][q], stride 34 -> conflict-free b64 reads
  __shared__ float s_qp[64 * 34];
  __shared__ float s_ka[64 * 68];   // [d][k], stride 68 -> 16B-aligned b128 reads
  __shared__ float s_kp[64 * 68];
  __shared__ float s_p [32 * 65];   // p tile [q][j]
  __shared__ float s_tbl[1024];
  const int h = blockIdx.y;
  const int q0 = blockIdx.x * 32;
  const int t = threadIdx.x;
  for (int n = t; n < 1024; n += 256) s_tbl[n] = tbl[n];
  // q-side staging (natural [h][i][d] -> transposed LDS); store conflicts only 2-way (free)
  #pragma unroll
  for (int it = 0; it < 8; ++it) {
    int n = t + 256 * it;
    int qi = n >> 6, d = n & 63;
    size_t g = (size_t)h * (2048 * 64) + (size_t)(q0 + qi) * 64 + d;
    s_qa[d * 34 + qi] = amp[g];
    s_qp[d * 34 + qi] = pA[g];
  }
  float o[8] = {0, 0, 0, 0, 0, 0, 0, 0};
  float den = 0.0f;
  const int tq = t >> 4, tk = t & 15;      // score phase: 2q x 4k per thread
  const int pq = t & 31, dvg = t >> 5;     // PV phase: 1q x 8dv per thread
  __syncthreads();
  for (int kt = 0; kt < 32; ++kt) {
    const int k0 = kt * 64;
    // k-side staging from transposed globals: coalesced reads, conflict-free stores
    #pragma unroll
    for (int it = 0; it < 16; ++it) {
      int n = t + 256 * it;
      int d = n >> 6, k = n & 63;
      size_t g = (size_t)h * (2048 * 64) + (size_t)d * 2048 + (k0 + k);
      s_ka[d * 68 + k] = ampT[g];
      s_kp[d * 68 + k] = pBT[g];
    }
    __syncthreads();
    float sc[8] = {0, 0, 0, 0, 0, 0, 0, 0};
    #pragma unroll 4
    for (int d = 0; d < 64; ++d) {
      const float2 qa = *reinterpret_cast<const float2*>(&s_qa[d * 34 + 2 * tq]);
      const float2 qp = *reinterpret_cast<const float2*>(&s_qp[d * 34 + 2 * tq]);
      const float4 ka = *reinterpret_cast<const float4*>(&s_ka[d * 68 + 4 * tk]);
      const float4 kp = *reinterpret_cast<const float4*>(&s_kp[d * 68 + 4 * tk]);
      const float kav[4] = {ka.x, ka.y, ka.z, ka.w};
      const float kpv[4] = {kp.x, kp.y, kp.z, kp.w};
      #pragma unroll
      for (int c = 0; c < 4; ++c) {
        // t' = (qp_i*c1 + s2 + 1024) - qp_j*c1 ; idx = (uint)t' & 1023
        unsigned u0 = ((unsigned)(qp.x - kpv[c])) & 1023u;
        unsigned u1 = ((unsigned)(qp.y - kpv[c])) & 1023u;
        sc[c]     = fmaf(qa.x * kav[c], s_tbl[u0], sc[c]);
        sc[4 + c] = fmaf(qa.y * kav[c], s_tbl[u1], sc[4 + c]);
      }
    }
    // p = exp(score / sqrt(64)); logits tiny -> no max subtraction needed
    #pragma unroll
    for (int c = 0; c < 4; ++c) {
      s_p[(2 * tq) * 65 + 4 * tk + c]     = expf(sc[c] * 0.125f);
      s_p[(2 * tq + 1) * 65 + 4 * tk + c] = expf(sc[4 + c] * 0.125f);
    }
    __syncthreads();
    // PV: v[j][dv] = x[(k0+j)*512 + h*64 + dv] straight from L2-resident x
    const float* xbase = x + (size_t)k0 * 512 + h * 64 + dvg * 8;
    #pragma unroll 8
    for (int j = 0; j < 64; ++j) {
      float pv = s_p[pq * 65 + j];
      den += pv;
      const float4 va = *reinterpret_cast<const float4*>(xbase + (size_t)j * 512);
      const float4 vb = *reinterpret_cast<const float4*>(xbase + (size_t)j * 512 + 4);
      o[0] = fmaf(pv, va.x, o[0]); o[1] = fmaf(pv, va.y, o[1]);
      o[2] = fmaf(pv, va.z, o[2]); o[3] = fmaf(pv, va.w, o[3]);
      o[4] = fmaf(pv, vb.x, o[4]); o[5] = fmaf(pv, vb.y, o[5]);
      o[6] = fmaf(pv, vb.z, o[6]); o[7] = fmaf(pv, vb.w, o[7]);
    }
    __syncthreads();
  }
  float invd = 1.0f / den;
  float* op = att + (size_t)(q0 + pq) * 512 + h * 64 + dvg * 8;
  float4 ra = {o[0] * invd, o[1] * invd, o[2] * invd, o[3] * invd};
  float4 rb = {o[4] * invd, o[5] * invd, o[6] * invd, o[7] * invd};
  *reinterpret_cast<float4*>(op) = ra;
  *reinterpret_cast<float4*>(op + 4) = rb;
}

// ---------------- K5: out = att @ W_out + b_out ----------------
__global__ __launch_bounds__(256) void k_out_gemm(const float* __restrict__ att,
    const float* __restrict__ Wo, const float* __restrict__ bo, float* __restrict__ out) {
  __shared__ float as_[8 * 512];
  const int r0 = blockIdx.x * 8;
  const int t = threadIdx.x;
  #pragma unroll
  for (int it = 0; it < 16; ++it) {
    int n = t + 256 * it;
    as_[n] = att[(size_t)r0 * 512 + n];
  }
  __syncthreads();
  float acc[8][2];
  float b0 = bo[t], b1 = bo[t + 256];
  #pragma unroll
  for (int r = 0; r < 8; ++r) { acc[r][0] = b0; acc[r][1] = b1; }
  for (int k = 0; k < 512; ++k) {
    float w0 = Wo[(size_t)k * 512 + t];
    float w1 = Wo[(size_t)k * 512 + t + 256];
    #pragma unroll
    for (int r = 0; r < 8; ++r) {
      float xv = as_[r * 512 + k];
      acc[r][0] = fmaf(xv, w0, acc[r][0]);
      acc[r][1] = fmaf(xv, w1, acc[r][1]);
    }
  }
  #pragma unroll
  for (int r = 0; r < 8; ++r) {
    out[(size_t)(r0 + r) * 512 + t]       = acc[r][0];
    out[(size_t)(r0 + r) * 512 + t + 256] = acc[r][1];
  }
}

extern "C" void kernel_launch(void* const* d_in, const int* in_sizes, int n_in,
                              void* d_out, int out_size, void* d_ws, size_t ws_size,
                              hipStream_t stream) {
  (void)in_sizes; (void)n_in; (void)out_size; (void)ws_size;
  const float* x   = (const float*)d_in[0];
  const float* Wq  = (const float*)d_in[1];
  const float* bq  = (const float*)d_in[2];
  const float* lnw = (const float*)d_in[3];
  const float* lnb = (const float*)d_in[4];
  const float* fr  = (const float*)d_in[5];
  const float* ps  = (const float*)d_in[6];
  const float* Wo  = (const float*)d_in[7];
  const float* bo  = (const float*)d_in[8];
  const float* tbl = (const float*)d_in[9];
  float* ws   = (float*)d_ws;
  float* qs   = ws + OFF_QS;
  float* att  = ws + OFF_ATT;
  float* amp  = ws + OFF_AMP;
  float* pA   = ws + OFF_PA;
  float* pB   = ws + OFF_PB;
  float* ampT = ws + OFF_AMPT;
  float* pBT  = ws + OFF_PBT;
  float* out  = (float*)d_out;

  k_gemm_qs<<<256, 256, 0, stream>>>(x, Wq, bq, qs);
  k_ln_act<<<2048, 256, 0, stream>>>(qs, lnw, lnb, fr, ps, amp, pA, pB);
  k_transpose<<<dim3(32, 8, 2), 256, 0, stream>>>(amp, pB, ampT, pBT);
  k_flash<<<dim3(64, 8), 256, 0, stream>>>(amp, pA, ampT, pBT, x, tbl, att);
  k_out_gemm<<<256, 256, 0, stream>>>(att, Wo, bo, out);
}

// Round 2
// 701.890 us; speedup vs baseline: 1.0659x; 1.0659x over previous
//
#include <hip/hip_runtime.h>
#include <cstdint>
#include <cstddef>

// Problem: B=1, L=2048, DIM=512, H=8, D=64, STEPS=1024.
//
// R2 change: replace the per-(i,j,d) cos-table gather with the smooth-cos
// factorization.  table[k] = cos(k*2pi/1023) and k = floor(mod(pd*1024/2pi,1024))
// ==> table value = cos(pd*1024/1023 + e), |e| <= 2pi/1023.  Dropping e:
//   interf ~= cos(A_i - B_j),  A_i = (p_i*f+s)*g,  B_j = p_j*f*g,  g = 1024/1023
//   S_ij   = sum_d qa_i qa_j cos(A_i-B_j)
//          = sum_d (qa_i cosA)(qa_j cosB) + (qa_i sinA)(qa_j sinB)
// i.e. a rank-128 GEMM per head: S = U @ W^T, U,W in [L,128].
//
// Pipeline:
//  K1 gemm_qs : qs = x @ W_qs + b_qs
//  K2 ln_act  : LN + sigmoid/L2norm + tanh*pi, emits U[h][i][128], W[h][i][128]
//  K4 flash2  : per (head, 32-q tile): k-tiles of 256: S-tile = U-tile @ W-tile^T
//               (fp32 FMA, f-chunked LDS staging), p=exp(S/8), online den + PV.
//  K5 out_gemm: out = att @ W_out + b_out
//
// ws floats: [0, 2097152) qs (att reuses [0,1M) after qs dead)
//            [2097152, 4194304) U   [4194304, 6291456) W     -> 25.2 MB

static constexpr size_t OFF_QS  = 0;
static constexpr size_t OFF_ATT = 0;
static constexpr size_t OFF_U   = (size_t)2097152;
static constexpr size_t OFF_W   = (size_t)4194304;

// ---------------- K1: qs = x @ W_qs + b_qs ----------------
__global__ __launch_bounds__(256) void k_gemm_qs(const float* __restrict__ x,
                                                 const float* __restrict__ Wq,
                                                 const float* __restrict__ bq,
                                                 float* __restrict__ qs) {
  __shared__ float xs[8 * 512];
  const int r0 = blockIdx.x * 8;
  const int t = threadIdx.x;
  #pragma unroll
  for (int it = 0; it < 16; ++it) {
    int n = t + 256 * it;
    xs[n] = x[(size_t)r0 * 512 + n];
  }
  __syncthreads();
  float acc[8][4];
  #pragma unroll
  for (int c = 0; c < 4; ++c) {
    float bv = bq[t + 256 * c];
    #pragma unroll
    for (int r = 0; r < 8; ++r) acc[r][c] = bv;
  }
  for (int k = 0; k < 512; ++k) {
    const float* wrow = Wq + (size_t)k * 1024 + t;
    float w0 = wrow[0], w1 = wrow[256], w2 = wrow[512], w3 = wrow[768];
    #pragma unroll
    for (int r = 0; r < 8; ++r) {
      float xv = xs[r * 512 + k];
      acc[r][0] = fmaf(xv, w0, acc[r][0]);
      acc[r][1] = fmaf(xv, w1, acc[r][1]);
      acc[r][2] = fmaf(xv, w2, acc[r][2]);
      acc[r][3] = fmaf(xv, w3, acc[r][3]);
    }
  }
  #pragma unroll
  for (int r = 0; r < 8; ++r) {
    #pragma unroll
    for (int c = 0; c < 4; ++c)
      qs[(size_t)(r0 + r) * 1024 + t + 256 * c] = acc[r][c];
  }
}

// ---------------- K2: LayerNorm + activations + cos/sin feature build ----------------
__global__ __launch_bounds__(256) void k_ln_act(const float* __restrict__ qs,
    const float* __restrict__ lnw, const float* __restrict__ lnb,
    const float* __restrict__ fr, const float* __restrict__ psh,
    float* __restrict__ U, float* __restrict__ W) {
  __shared__ float red[256];
  __shared__ float red2[256];
  const int i = blockIdx.x, t = threadIdx.x;
  const float* row = qs + (size_t)i * 1024;
  float v0 = row[t], v1 = row[t + 256], v2 = row[t + 512], v3 = row[t + 768];
  red[t]  = v0 + v1 + v2 + v3;
  red2[t] = v0 * v0 + v1 * v1 + v2 * v2 + v3 * v3;
  __syncthreads();
  for (int st = 128; st > 0; st >>= 1) {
    if (t < st) { red[t] += red[t + st]; red2[t] += red2[t + st]; }
    __syncthreads();
  }
  float mu  = red[0] * (1.0f / 1024.0f);
  float var = red2[0] * (1.0f / 1024.0f) - mu * mu;
  float rstd = 1.0f / sqrtf(var + 1e-5f);
  float y0 = (v0 - mu) * rstd * lnw[t]       + lnb[t];
  float y1 = (v1 - mu) * rstd * lnw[t + 256] + lnb[t + 256];
  float y2 = (v2 - mu) * rstd * lnw[t + 512] + lnb[t + 512];
  float y3 = (v3 - mu) * rstd * lnw[t + 768] + lnb[t + 768];
  float a0 = 1.0f / (1.0f + expf(-y0));
  float a1 = 1.0f / (1.0f + expf(-y1));
  __syncthreads();
  red[t] = a0 * a0 + a1 * a1;
  __syncthreads();
  for (int st = 128; st > 0; st >>= 1) {
    if (t < st) red[t] += red[t + st];
    __syncthreads();
  }
  float inv = 1.0f / (sqrtf(red[0]) + 1e-8f);
  float af0 = a0 * inv, af1 = a1 * inv;
  const float PI_F = 3.14159265358979323846f;
  float p2 = tanhf(y2) * PI_F;     // phase for head h0 = t>>6
  float p3 = tanhf(y3) * PI_F;     // phase for head h1 = h0+4
  const double GAM = 1024.0 / 1023.0;   // table-step rescale (linspace endpoint)
  int h0 = t >> 6, d0 = t & 63;
  int h1 = h0 + 4;
  float c10 = (float)((double)fr[h0] * GAM);
  float s10 = (float)((double)psh[h0] * GAM);
  float c11 = (float)((double)fr[h1] * GAM);
  float s11 = (float)((double)psh[h1] * GAM);
  float A0 = fmaf(p2, c10, s10), B0 = p2 * c10;
  float A1 = fmaf(p3, c11, s11), B1 = p3 * c11;
  float cA0, sA0, cB0, sB0, cA1, sA1, cB1, sB1;
  sincosf(A0, &sA0, &cA0);
  sincosf(B0, &sB0, &cB0);
  sincosf(A1, &sA1, &cA1);
  sincosf(B1, &sB1, &cB1);
  size_t u0 = ((size_t)h0 * 2048 + i) * 128 + d0;
  size_t u1 = ((size_t)h1 * 2048 + i) * 128 + d0;
  U[u0]      = af0 * cA0;  U[u0 + 64] = af0 * sA0;
  W[u0]      = af0 * cB0;  W[u0 + 64] = af0 * sB0;
  U[u1]      = af1 * cA1;  U[u1 + 64] = af1 * sA1;
  W[u1]      = af1 * cB1;  W[u1 + 64] = af1 * sB1;
}

// ---------------- K4: fused rank-128 score GEMM + softmax + PV ----------------
__global__ __launch_bounds__(256, 2) void k_flash2(const float* __restrict__ U,
    const float* __restrict__ W, const float* __restrict__ x,
    float* __restrict__ att) {
  __shared__ float s_u[128 * 36];   // U-tile transposed [f][q], stride 36 (16B-aligned)
  __shared__ float s_w[16 * 264];   // W f-chunk transposed [f][k], stride 264
  __shared__ float s_p[32 * 260];   // p tile [q][j], stride 260 (b32 reads: 4-bank rotate)
  const int h = blockIdx.y;
  const int q0 = blockIdx.x * 32;
  const int t = threadIdx.x;
  // stage U-tile [32 q][128 f] -> s_u[f][q]
  #pragma unroll
  for (int it = 0; it < 16; ++it) {
    int n = t + 256 * it;
    int q = n >> 7, f = n & 127;
    s_u[f * 36 + q] = U[((size_t)h * 2048 + q0 + q) * 128 + f];
  }
  const int tq = t >> 5;        // 8 groups x 4 q
  const int tk = t & 31;        // 32 groups x 8 k
  const int pq = t & 31;        // PV: q row
  const int dv0 = (t >> 5) * 8; // PV: 8 dv
  float o[8] = {0, 0, 0, 0, 0, 0, 0, 0};
  float den = 0.0f;
  __syncthreads();
  for (int kt = 0; kt < 8; ++kt) {
    const int k0 = kt * 256;
    float sc[4][8];
    #pragma unroll
    for (int r = 0; r < 4; ++r)
      #pragma unroll
      for (int c = 0; c < 8; ++c) sc[r][c] = 0.0f;
    for (int ch = 0; ch < 8; ++ch) {
      const int fc = ch * 16;
      __syncthreads();      // previous chunk's readers (or previous kt) done
      #pragma unroll
      for (int it = 0; it < 16; ++it) {
        int n = t + 256 * it;
        int k = n >> 4, f = n & 15;
        s_w[f * 264 + k] = W[((size_t)h * 2048 + k0 + k) * 128 + fc + f];
      }
      __syncthreads();
      #pragma unroll
      for (int f = 0; f < 16; ++f) {
        const float4 qa = *reinterpret_cast<const float4*>(&s_u[(fc + f) * 36 + tq * 4]);
        const float4 ka = *reinterpret_cast<const float4*>(&s_w[f * 264 + tk * 8]);
        const float4 kb = *reinterpret_cast<const float4*>(&s_w[f * 264 + tk * 8 + 4]);
        const float qv[4] = {qa.x, qa.y, qa.z, qa.w};
        const float kv[8] = {ka.x, ka.y, ka.z, ka.w, kb.x, kb.y, kb.z, kb.w};
        #pragma unroll
        for (int r = 0; r < 4; ++r)
          #pragma unroll
          for (int c = 0; c < 8; ++c)
            sc[r][c] = fmaf(qv[r], kv[c], sc[r][c]);
      }
    }
    __syncthreads();          // all PV readers of previous s_p done + scores done
    #pragma unroll
    for (int r = 0; r < 4; ++r) {
      float4 pa = {expf(sc[r][0] * 0.125f), expf(sc[r][1] * 0.125f),
                   expf(sc[r][2] * 0.125f), expf(sc[r][3] * 0.125f)};
      float4 pb = {expf(sc[r][4] * 0.125f), expf(sc[r][5] * 0.125f),
                   expf(sc[r][6] * 0.125f), expf(sc[r][7] * 0.125f)};
      *reinterpret_cast<float4*>(&s_p[(tq * 4 + r) * 260 + tk * 8])     = pa;
      *reinterpret_cast<float4*>(&s_p[(tq * 4 + r) * 260 + tk * 8 + 4]) = pb;
    }
    __syncthreads();
    // PV: v[j][dv] = x[(k0+j)*512 + h*64 + dv] from L1/L2-resident x
    const float* xb = x + (size_t)k0 * 512 + h * 64 + dv0;
    #pragma unroll 4
    for (int j = 0; j < 256; ++j) {
      float pv = s_p[pq * 260 + j];
      den += pv;
      const float4 va = *reinterpret_cast<const float4*>(xb + (size_t)j * 512);
      const float4 vb = *reinterpret_cast<const float4*>(xb + (size_t)j * 512 + 4);
      o[0] = fmaf(pv, va.x, o[0]); o[1] = fmaf(pv, va.y, o[1]);
      o[2] = fmaf(pv, va.z, o[2]); o[3] = fmaf(pv, va.w, o[3]);
      o[4] = fmaf(pv, vb.x, o[4]); o[5] = fmaf(pv, vb.y, o[5]);
      o[6] = fmaf(pv, vb.z, o[6]); o[7] = fmaf(pv, vb.w, o[7]);
    }
  }
  float invd = 1.0f / den;
  float* op = att + (size_t)(q0 + pq) * 512 + h * 64 + dv0;
  float4 ra = {o[0] * invd, o[1] * invd, o[2] * invd, o[3] * invd};
  float4 rb = {o[4] * invd, o[5] * invd, o[6] * invd, o[7] * invd};
  *reinterpret_cast<float4*>(op) = ra;
  *reinterpret_cast<float4*>(op + 4) = rb;
}

// ---------------- K5: out = att @ W_out + b_out ----------------
__global__ __launch_bounds__(256) void k_out_gemm(const float* __restrict__ att,
    const float* __restrict__ Wo, const float* __restrict__ bo, float* __restrict__ out) {
  __shared__ float as_[8 * 512];
  const int r0 = blockIdx.x * 8;
  const int t = threadIdx.x;
  #pragma unroll
  for (int it = 0; it < 16; ++it) {
    int n = t + 256 * it;
    as_[n] = att[(size_t)r0 * 512 + n];
  }
  __syncthreads();
  float acc[8][2];
  float b0 = bo[t], b1 = bo[t + 256];
  #pragma unroll
  for (int r = 0; r < 8; ++r) { acc[r][0] = b0; acc[r][1] = b1; }
  for (int k = 0; k < 512; ++k) {
    float w0 = Wo[(size_t)k * 512 + t];
    float w1 = Wo[(size_t)k * 512 + t + 256];
    #pragma unroll
    for (int r = 0; r < 8; ++r) {
      float xv = as_[r * 512 + k];
      acc[r][0] = fmaf(xv, w0, acc[r][0]);
      acc[r][1] = fmaf(xv, w1, acc[r][1]);
    }
  }
  #pragma unroll
  for (int r = 0; r < 8; ++r) {
    out[(size_t)(r0 + r) * 512 + t]       = acc[r][0];
    out[(size_t)(r0 + r) * 512 + t + 256] = acc[r][1];
  }
}

extern "C" void kernel_launch(void* const* d_in, const int* in_sizes, int n_in,
                              void* d_out, int out_size, void* d_ws, size_t ws_size,
                              hipStream_t stream) {
  (void)in_sizes; (void)n_in; (void)out_size; (void)ws_size;
  const float* x   = (const float*)d_in[0];
  const float* Wq  = (const float*)d_in[1];
  const float* bq  = (const float*)d_in[2];
  const float* lnw = (const float*)d_in[3];
  const float* lnb = (const float*)d_in[4];
  const float* fr  = (const float*)d_in[5];
  const float* ps  = (const float*)d_in[6];
  const float* Wo  = (const float*)d_in[7];
  const float* bo  = (const float*)d_in[8];
  // d_in[9] = cos_table: no longer read (smooth-cos factorization)
  float* ws  = (float*)d_ws;
  float* qs  = ws + OFF_QS;
  float* att = ws + OFF_ATT;
  float* Uf  = ws + OFF_U;
  float* Wf  = ws + OFF_W;
  float* out = (float*)d_out;

  k_gemm_qs<<<256, 256, 0, stream>>>(x, Wq, bq, qs);
  k_ln_act<<<2048, 256, 0, stream>>>(qs, lnw, lnb, fr, ps, Uf, Wf);
  k_flash2<<<dim3(64, 8), 256, 0, stream>>>(Uf, Wf, x, att);
  k_out_gemm<<<256, 256, 0, stream>>>(att, Wo, bo, out);
}

// Round 3
// 204.299 us; speedup vs baseline: 3.6619x; 3.4356x over previous
//
#include <hip/hip_runtime.h>
#include <cstdint>
#include <cstddef>

// B=1, L=2048, DIM=512, H=8, D=64, STEPS=1024.  R3: all-MFMA pipeline (bf16).
//
//  k_cast_x  : x -> xb bf16 [2048][512], vT bf16 [8][64][2048]
//  k_cast_w  : Wq -> WqT bf16 [1024][512], Wo -> WoT bf16 [512][512]
//  k_gemm    : qs f32 = xb @ WqT^T + bq      (MFMA 16x16x32 bf16, 64x64 tiles)
//  k_ln_act  : LN + sigmoid/L2norm + tanh*pi -> Ub,Wb bf16 [h][i][128]
//              (smooth-cos factorization from R2: S = U @ W^T, rank 128)
//  k_flash3  : per (h, 64-q tile, k-half): 16 k-tiles of 64:
//              S-tile via MFMA, p=exp(S/8) -> LDS bf16 (A-layout round-trip),
//              PV + den via MFMA; writes unnormalized O,den partials.
//  k_combine : att bf16 = (O0+O1)/(den0+den1)
//  k_gemm    : out f32 = attb @ WoT^T + bo
//
// ws bytes: [0,8M) qs f32  /  Opart f32 (sequential reuse)
//           [8M,8.125M) Dpart   [8.25M,12.25M) Ub   [12.25M,16.25M) Wb
//           [16.25M,18.25M) xb  [18.25M,20.25M) vT  [20.25M,21.25M) WqT
//           [21.25M,21.75M) WoT [21.75M,23.75M) attb      -> 23.75 MB

typedef __attribute__((ext_vector_type(8))) short short8;
typedef __attribute__((ext_vector_type(4))) float f32x4;

#define MFMA16(a, b, c) __builtin_amdgcn_mfma_f32_16x16x32_bf16((a), (b), (c), 0, 0, 0)

static constexpr size_t B_QS   = 0;
static constexpr size_t B_OP   = 0;                       // Opart reuses qs
static constexpr size_t B_DP   = (size_t)8 * 1024 * 1024;
static constexpr size_t B_UB   = B_DP + 256 * 1024;
static constexpr size_t B_WB   = B_UB + (size_t)4 * 1024 * 1024;
static constexpr size_t B_XB   = B_WB + (size_t)4 * 1024 * 1024;
static constexpr size_t B_VT   = B_XB + (size_t)2 * 1024 * 1024;
static constexpr size_t B_WQT  = B_VT + (size_t)2 * 1024 * 1024;
static constexpr size_t B_WOT  = B_WQT + (size_t)1 * 1024 * 1024;
static constexpr size_t B_ATTB = B_WOT + 512 * 1024;

__device__ __forceinline__ unsigned short f2bf(float f) {
  unsigned u = __float_as_uint(f);
  return (unsigned short)((u + 0x7FFFu + ((u >> 16) & 1u)) >> 16);
}

// ---------------- cast x -> xb bf16 + vT bf16 [h][d][k] ----------------
__global__ __launch_bounds__(256) void k_cast_x(const float* __restrict__ x,
    unsigned short* __restrict__ xb, unsigned short* __restrict__ vT) {
  __shared__ float tl[64 * 65];
  const int i0 = blockIdx.x * 64, t = threadIdx.x;
  for (int h = 0; h < 8; ++h) {
    __syncthreads();
    #pragma unroll
    for (int it = 0; it < 16; ++it) {
      int n = t + 256 * it;
      int r = n >> 6, c = n & 63;
      float v = x[(size_t)(i0 + r) * 512 + h * 64 + c];
      tl[r * 65 + c] = v;
      xb[(size_t)(i0 + r) * 512 + h * 64 + c] = f2bf(v);
    }
    __syncthreads();
    #pragma unroll
    for (int it = 0; it < 16; ++it) {
      int n = t + 256 * it;
      int d = n >> 6, ii = n & 63;
      vT[(size_t)(h * 64 + d) * 2048 + i0 + ii] = f2bf(tl[ii * 65 + d]);
    }
  }
}

// ---------------- cast+transpose Wq -> WqT, Wo -> WoT (bf16) ----------------
__global__ __launch_bounds__(256) void k_cast_w(const float* __restrict__ Wq,
    const float* __restrict__ Wo, unsigned short* __restrict__ WqT,
    unsigned short* __restrict__ WoT) {
  __shared__ float tl[64 * 65];
  const int t = threadIdx.x;
  int b = blockIdx.x;
  const float* src; unsigned short* dst; int k0, n0, N;
  if (b < 128) { src = Wq; dst = WqT; k0 = (b >> 4) * 64; n0 = (b & 15) * 64; N = 1024; }
  else { b -= 128; src = Wo; dst = WoT; k0 = (b >> 3) * 64; n0 = (b & 7) * 64; N = 512; }
  #pragma unroll
  for (int it = 0; it < 16; ++it) {
    int n = t + 256 * it;
    int r = n >> 6, c = n & 63;
    tl[r * 65 + c] = src[(size_t)(k0 + r) * N + n0 + c];
  }
  __syncthreads();
  #pragma unroll
  for (int it = 0; it < 16; ++it) {
    int n = t + 256 * it;
    int rr = n >> 6, cc = n & 63;   // dst row (n-dim), dst col (k-dim)
    dst[(size_t)(n0 + rr) * 512 + k0 + cc] = f2bf(tl[cc * 65 + rr]);
  }
}

// ---------------- generic bf16 MFMA GEMM: C[M][N] = A[M][512] @ Bt[N][512]^T + bias ----
__global__ __launch_bounds__(256) void k_gemm(const unsigned short* __restrict__ A,
    const unsigned short* __restrict__ Bt, const float* __restrict__ bias,
    float* __restrict__ C, int N) {
  __shared__ __align__(16) unsigned char sm[2 * 64 * 136];
  unsigned char* s_a = sm;               // 64 rows x 136B (64 bf16 + pad)
  unsigned char* s_b = sm + 64 * 136;
  const int m0 = blockIdx.x * 64, n0 = blockIdx.y * 64;
  const int t = threadIdx.x;
  const int wave = t >> 6, lane = t & 63;
  const int m = lane & 15, quad = lane >> 4;
  const int sr = t >> 2, spart = t & 3;
  f32x4 acc[4] = {{0,0,0,0},{0,0,0,0},{0,0,0,0},{0,0,0,0}};
  for (int kc = 0; kc < 512; kc += 64) {
    #pragma unroll
    for (int it = 0; it < 2; ++it) {
      *(short8*)(s_a + sr * 136 + spart * 32 + it * 16) =
        *(const short8*)(A + (size_t)(m0 + sr) * 512 + kc + spart * 16 + it * 8);
      *(short8*)(s_b + sr * 136 + spart * 32 + it * 16) =
        *(const short8*)(Bt + (size_t)(n0 + sr) * 512 + kc + spart * 16 + it * 8);
    }
    __syncthreads();
    #pragma unroll
    for (int k2 = 0; k2 < 2; ++k2) {
      short8 af = *(const short8*)(s_a + (wave * 16 + m) * 136 + k2 * 64 + quad * 16);
      #pragma unroll
      for (int nt = 0; nt < 4; ++nt) {
        short8 bf = *(const short8*)(s_b + (nt * 16 + m) * 136 + k2 * 64 + quad * 16);
        acc[nt] = MFMA16(af, bf, acc[nt]);
      }
    }
    __syncthreads();
  }
  #pragma unroll
  for (int nt = 0; nt < 4; ++nt) {
    int col = n0 + nt * 16 + m;
    float bv = bias[col];
    #pragma unroll
    for (int r = 0; r < 4; ++r) {
      int row = m0 + wave * 16 + quad * 4 + r;
      C[(size_t)row * N + col] = acc[nt][r] + bv;
    }
  }
}

// ---------------- LN + activations -> Ub, Wb bf16 [h][i][128] ----------------
__global__ __launch_bounds__(256) void k_ln_act(const float* __restrict__ qs,
    const float* __restrict__ lnw, const float* __restrict__ lnb,
    const float* __restrict__ fr, const float* __restrict__ psh,
    unsigned short* __restrict__ Ub, unsigned short* __restrict__ Wb) {
  __shared__ float sred[12];
  const int i = blockIdx.x, t = threadIdx.x;
  const int wave = t >> 6, lane = t & 63;
  const float* row = qs + (size_t)i * 1024;
  float v0 = row[t], v1 = row[t + 256], v2 = row[t + 512], v3 = row[t + 768];
  float s = v0 + v1 + v2 + v3;
  float s2 = v0 * v0 + v1 * v1 + v2 * v2 + v3 * v3;
  #pragma unroll
  for (int off = 32; off; off >>= 1) {
    s += __shfl_down(s, off, 64);
    s2 += __shfl_down(s2, off, 64);
  }
  if (lane == 0) { sred[wave] = s; sred[4 + wave] = s2; }
  __syncthreads();
  s = sred[0] + sred[1] + sred[2] + sred[3];
  s2 = sred[4] + sred[5] + sred[6] + sred[7];
  float mu = s * (1.0f / 1024.0f);
  float var = s2 * (1.0f / 1024.0f) - mu * mu;
  float rstd = 1.0f / sqrtf(var + 1e-5f);
  float y0 = (v0 - mu) * rstd * lnw[t]       + lnb[t];
  float y1 = (v1 - mu) * rstd * lnw[t + 256] + lnb[t + 256];
  float y2 = (v2 - mu) * rstd * lnw[t + 512] + lnb[t + 512];
  float y3 = (v3 - mu) * rstd * lnw[t + 768] + lnb[t + 768];
  float a0 = 1.0f / (1.0f + __expf(-y0));
  float a1 = 1.0f / (1.0f + __expf(-y1));
  float na = a0 * a0 + a1 * a1;
  #pragma unroll
  for (int off = 32; off; off >>= 1) na += __shfl_down(na, off, 64);
  __syncthreads();                      // everyone done reading sred[0..7]
  if (lane == 0) sred[8 + wave] = na;
  __syncthreads();
  na = sred[8] + sred[9] + sred[10] + sred[11];
  float inv = 1.0f / (sqrtf(na) + 1e-8f);
  float af0 = a0 * inv, af1 = a1 * inv;
  const float PI_F = 3.14159265358979323846f;
  float p2 = tanhf(y2) * PI_F;          // phase for head h0
  float p3 = tanhf(y3) * PI_F;          // phase for head h0+4
  const double GAM = 1024.0 / 1023.0;   // table-step rescale (linspace endpoint)
  int h0 = t >> 6, d0 = t & 63, h1 = h0 + 4;
  float c10 = (float)((double)fr[h0] * GAM);
  float s10 = (float)((double)psh[h0] * GAM);
  float c11 = (float)((double)fr[h1] * GAM);
  float s11 = (float)((double)psh[h1] * GAM);
  float A0 = fmaf(p2, c10, s10), Bp0 = p2 * c10;
  float A1 = fmaf(p3, c11, s11), Bp1 = p3 * c11;
  float cA0, sA0, cB0, sB0, cA1, sA1, cB1, sB1;
  sincosf(A0, &sA0, &cA0);
  sincosf(Bp0, &sB0, &cB0);
  sincosf(A1, &sA1, &cA1);
  sincosf(Bp1, &sB1, &cB1);
  size_t b0 = ((size_t)h0 * 2048 + i) * 128 + d0;
  size_t b1 = ((size_t)h1 * 2048 + i) * 128 + d0;
  Ub[b0] = f2bf(af0 * cA0);  Ub[b0 + 64] = f2bf(af0 * sA0);
  Wb[b0] = f2bf(af0 * cB0);  Wb[b0 + 64] = f2bf(af0 * sB0);
  Ub[b1] = f2bf(af1 * cA1);  Ub[b1 + 64] = f2bf(af1 * sA1);
  Wb[b1] = f2bf(af1 * cB1);  Wb[b1 + 64] = f2bf(af1 * sB1);
}

// ---------------- fused MFMA flash: scores + softmax + PV (k-split 2) ----------------
__global__ __launch_bounds__(256, 2) void k_flash3(const unsigned short* __restrict__ Ub,
    const unsigned short* __restrict__ Wb, const unsigned short* __restrict__ vT,
    float* __restrict__ Opart, float* __restrict__ Dpart) {
  __shared__ __align__(16) unsigned char sm[35840];
  unsigned char* s_w = sm;             // 64 k-rows x 272B (128 bf16 + 16B pad)
  unsigned char* s_v = sm + 17408;     // 64 d-rows x 144B (64 bf16 + 16B pad)
  unsigned char* s_p = sm + 26624;     // 4 waves x 16 q x 144B
  const int qt = blockIdx.x, h = blockIdx.y, ks = blockIdx.z;
  const int q0 = qt * 64;
  const int t = threadIdx.x;
  const int wave = t >> 6, lane = t & 63;
  const int m = lane & 15, quad = lane >> 4;
  const int sr = t >> 2, spart = t & 3;
  unsigned char* s_pw = s_p + wave * 2304;
  // preload U A-frags (q-side, k-tile-invariant)
  short8 afr[4];
  const unsigned short* urow = Ub + ((size_t)h * 2048 + q0 + wave * 16 + m) * 128;
  #pragma unroll
  for (int fs = 0; fs < 4; ++fs)
    afr[fs] = *(const short8*)(urow + fs * 32 + quad * 8);
  short8 ones;
  #pragma unroll
  for (int j = 0; j < 8; ++j) ones[j] = (short)0x3F80;   // bf16 1.0
  f32x4 oacc[4] = {{0,0,0,0},{0,0,0,0},{0,0,0,0},{0,0,0,0}};
  f32x4 dacc = {0, 0, 0, 0};
  for (int kt = 0; kt < 16; ++kt) {
    const int k0 = ks * 1024 + kt * 64;
    // stage W-tile (16KB) + V-tile (8KB), padded strides (8-phase-optimal banks)
    const unsigned short* wg = Wb + ((size_t)h * 2048 + k0) * 128;
    #pragma unroll
    for (int it = 0; it < 4; ++it)
      *(short8*)(s_w + sr * 272 + spart * 64 + it * 16) =
        *(const short8*)(wg + sr * 128 + spart * 32 + it * 8);
    const unsigned short* vg = vT + ((size_t)h * 64 + sr) * 2048 + k0;
    #pragma unroll
    for (int it = 0; it < 2; ++it)
      *(short8*)(s_v + sr * 144 + spart * 32 + it * 16) =
        *(const short8*)(vg + spart * 16 + it * 8);
    __syncthreads();
    // scores: S[16q x 64k] per wave = 4 ksub-tiles x 4 f-steps
    f32x4 sc[4] = {{0,0,0,0},{0,0,0,0},{0,0,0,0},{0,0,0,0}};
    #pragma unroll
    for (int ksub = 0; ksub < 4; ++ksub)
      #pragma unroll
      for (int fs = 0; fs < 4; ++fs) {
        short8 bfr = *(const short8*)(s_w + (ksub * 16 + m) * 272 + fs * 64 + quad * 16);
        sc[ksub] = MFMA16(afr[fs], bfr, sc[ksub]);
      }
    // p = exp(S/8) -> LDS bf16 in [q][j] (C-layout write, A-layout re-read)
    #pragma unroll
    for (int ksub = 0; ksub < 4; ++ksub)
      #pragma unroll
      for (int r = 0; r < 4; ++r) {
        float p = __expf(sc[ksub][r] * 0.125f);
        *(unsigned short*)(s_pw + (quad * 4 + r) * 144 + (ksub * 16 + m) * 2) = f2bf(p);
      }
    __syncthreads();
    // PV + den via MFMA
    #pragma unroll
    for (int k2 = 0; k2 < 2; ++k2) {
      short8 pf = *(const short8*)(s_pw + m * 144 + k2 * 64 + quad * 16);
      dacc = MFMA16(pf, ones, dacc);
      #pragma unroll
      for (int dt = 0; dt < 4; ++dt) {
        short8 vf = *(const short8*)(s_v + (dt * 16 + m) * 144 + k2 * 64 + quad * 16);
        oacc[dt] = MFMA16(pf, vf, oacc[dt]);
      }
    }
    __syncthreads();
  }
  // write unnormalized partials
  const size_t obase = (((size_t)ks * 8 + h) * 2048 + q0 + wave * 16) * 64;
  #pragma unroll
  for (int dt = 0; dt < 4; ++dt)
    #pragma unroll
    for (int r = 0; r < 4; ++r)
      Opart[obase + (size_t)(quad * 4 + r) * 64 + dt * 16 + m] = oacc[dt][r];
  if (m == 0) {
    #pragma unroll
    for (int r = 0; r < 4; ++r)
      Dpart[((size_t)ks * 8 + h) * 2048 + q0 + wave * 16 + quad * 4 + r] = dacc[r];
  }
}

// ---------------- combine k-split partials -> att bf16 [2048][512] ----------------
__global__ __launch_bounds__(256) void k_combine(const float* __restrict__ Opart,
    const float* __restrict__ Dpart, unsigned short* __restrict__ attb) {
  int n = blockIdx.x * 256 + threadIdx.x;      // over 2048*512
  int q = n >> 9, c = n & 511;
  int h = c >> 6, d = c & 63;
  size_t i0 = (((size_t)h) * 2048 + q) * 64 + d;
  size_t i1 = (((size_t)8 + h) * 2048 + q) * 64 + d;
  float o = Opart[i0] + Opart[i1];
  float den = Dpart[h * 2048 + q] + Dpart[8 * 2048 + h * 2048 + q];
  attb[n] = f2bf(o / den);
}

extern "C" void kernel_launch(void* const* d_in, const int* in_sizes, int n_in,
                              void* d_out, int out_size, void* d_ws, size_t ws_size,
                              hipStream_t stream) {
  (void)in_sizes; (void)n_in; (void)out_size; (void)ws_size;
  const float* x   = (const float*)d_in[0];
  const float* Wq  = (const float*)d_in[1];
  const float* bq  = (const float*)d_in[2];
  const float* lnw = (const float*)d_in[3];
  const float* lnb = (const float*)d_in[4];
  const float* fr  = (const float*)d_in[5];
  const float* ps  = (const float*)d_in[6];
  const float* Wo  = (const float*)d_in[7];
  const float* bo  = (const float*)d_in[8];
  // d_in[9] = cos_table: unused (smooth-cos factorization)
  char* ws = (char*)d_ws;
  float*          qs    = (float*)(ws + B_QS);
  float*          Opart = (float*)(ws + B_OP);
  float*          Dpart = (float*)(ws + B_DP);
  unsigned short* Ub    = (unsigned short*)(ws + B_UB);
  unsigned short* Wb    = (unsigned short*)(ws + B_WB);
  unsigned short* xb    = (unsigned short*)(ws + B_XB);
  unsigned short* vT    = (unsigned short*)(ws + B_VT);
  unsigned short* WqT   = (unsigned short*)(ws + B_WQT);
  unsigned short* WoT   = (unsigned short*)(ws + B_WOT);
  unsigned short* attb  = (unsigned short*)(ws + B_ATTB);
  float* out = (float*)d_out;

  k_cast_x<<<32, 256, 0, stream>>>(x, xb, vT);
  k_cast_w<<<192, 256, 0, stream>>>(Wq, Wo, WqT, WoT);
  k_gemm<<<dim3(32, 16), 256, 0, stream>>>(xb, WqT, bq, qs, 1024);
  k_ln_act<<<2048, 256, 0, stream>>>(qs, lnw, lnb, fr, ps, Ub, Wb);
  k_flash3<<<dim3(32, 8, 2), 256, 0, stream>>>(Ub, Wb, vT, Opart, Dpart);
  k_combine<<<4096, 256, 0, stream>>>(Opart, Dpart, attb);
  k_gemm<<<dim3(32, 8), 256, 0, stream>>>(attb, WoT, bo, out, 512);
}

// Round 4
// 168.064 us; speedup vs baseline: 4.4514x; 1.2156x over previous
//
#include <hip/hip_runtime.h>
#include <cstdint>
#include <cstddef>

// B=1, L=2048, DIM=512, H=8, D=64, STEPS=1024.  R4: all-MFMA pipeline (bf16).
// R4 change: k_cast_x parallelized over heads (grid 32x8, was 32 blocks with
// an internal h-loop -> latency-bound at 1.3% occupancy, 53us for 10MB).
//
//  k_cast_x  : x -> xb bf16 [2048][512], vT bf16 [8][64][2048]
//  k_cast_w  : Wq -> WqT bf16 [1024][512], Wo -> WoT bf16 [512][512]
//  k_gemm    : qs f32 = xb @ WqT^T + bq      (MFMA 16x16x32 bf16, 64x64 tiles)
//  k_ln_act  : LN + sigmoid/L2norm + tanh*pi -> Ub,Wb bf16 [h][i][128]
//              (smooth-cos factorization: S = U @ W^T, rank 128)
//  k_flash3  : per (h, 64-q tile, k-half): 16 k-tiles of 64:
//              S-tile via MFMA, p=exp(S/8) -> LDS bf16 (A-layout round-trip),
//              PV + den via MFMA; writes unnormalized O,den partials.
//  k_combine : att bf16 = (O0+O1)/(den0+den1)
//  k_gemm    : out f32 = attb @ WoT^T + bo

typedef __attribute__((ext_vector_type(8))) short short8;
typedef __attribute__((ext_vector_type(4))) float f32x4;

#define MFMA16(a, b, c) __builtin_amdgcn_mfma_f32_16x16x32_bf16((a), (b), (c), 0, 0, 0)

static constexpr size_t B_QS   = 0;
static constexpr size_t B_OP   = 0;                       // Opart reuses qs
static constexpr size_t B_DP   = (size_t)8 * 1024 * 1024;
static constexpr size_t B_UB   = B_DP + 256 * 1024;
static constexpr size_t B_WB   = B_UB + (size_t)4 * 1024 * 1024;
static constexpr size_t B_XB   = B_WB + (size_t)4 * 1024 * 1024;
static constexpr size_t B_VT   = B_XB + (size_t)2 * 1024 * 1024;
static constexpr size_t B_WQT  = B_VT + (size_t)2 * 1024 * 1024;
static constexpr size_t B_WOT  = B_WQT + (size_t)1 * 1024 * 1024;
static constexpr size_t B_ATTB = B_WOT + 512 * 1024;

__device__ __forceinline__ unsigned short f2bf(float f) {
  unsigned u = __float_as_uint(f);
  return (unsigned short)((u + 0x7FFFu + ((u >> 16) & 1u)) >> 16);
}

// ---------------- cast x -> xb bf16 + vT bf16 [h][d][k]; one block per (i0,h) ----
__global__ __launch_bounds__(256) void k_cast_x(const float* __restrict__ x,
    unsigned short* __restrict__ xb, unsigned short* __restrict__ vT) {
  __shared__ float tl[64 * 65];
  const int i0 = blockIdx.x * 64, h = blockIdx.y, t = threadIdx.x;
  #pragma unroll
  for (int it = 0; it < 16; ++it) {
    int n = t + 256 * it;
    int r = n >> 6, c = n & 63;
    float v = x[(size_t)(i0 + r) * 512 + h * 64 + c];
    tl[r * 65 + c] = v;
    xb[(size_t)(i0 + r) * 512 + h * 64 + c] = f2bf(v);
  }
  __syncthreads();
  #pragma unroll
  for (int it = 0; it < 16; ++it) {
    int n = t + 256 * it;
    int d = n >> 6, ii = n & 63;
    vT[(size_t)(h * 64 + d) * 2048 + i0 + ii] = f2bf(tl[ii * 65 + d]);
  }
}

// ---------------- cast+transpose Wq -> WqT, Wo -> WoT (bf16) ----------------
__global__ __launch_bounds__(256) void k_cast_w(const float* __restrict__ Wq,
    const float* __restrict__ Wo, unsigned short* __restrict__ WqT,
    unsigned short* __restrict__ WoT) {
  __shared__ float tl[64 * 65];
  const int t = threadIdx.x;
  int b = blockIdx.x;
  const float* src; unsigned short* dst; int k0, n0, N;
  if (b < 128) { src = Wq; dst = WqT; k0 = (b >> 4) * 64; n0 = (b & 15) * 64; N = 1024; }
  else { b -= 128; src = Wo; dst = WoT; k0 = (b >> 3) * 64; n0 = (b & 7) * 64; N = 512; }
  #pragma unroll
  for (int it = 0; it < 16; ++it) {
    int n = t + 256 * it;
    int r = n >> 6, c = n & 63;
    tl[r * 65 + c] = src[(size_t)(k0 + r) * N + n0 + c];
  }
  __syncthreads();
  #pragma unroll
  for (int it = 0; it < 16; ++it) {
    int n = t + 256 * it;
    int rr = n >> 6, cc = n & 63;   // dst row (n-dim), dst col (k-dim)
    dst[(size_t)(n0 + rr) * 512 + k0 + cc] = f2bf(tl[cc * 65 + rr]);
  }
}

// ---------------- generic bf16 MFMA GEMM: C[M][N] = A[M][512] @ Bt[N][512]^T + bias ----
__global__ __launch_bounds__(256) void k_gemm(const unsigned short* __restrict__ A,
    const unsigned short* __restrict__ Bt, const float* __restrict__ bias,
    float* __restrict__ C, int N) {
  __shared__ __align__(16) unsigned char sm[2 * 64 * 136];
  unsigned char* s_a = sm;               // 64 rows x 136B (64 bf16 + pad)
  unsigned char* s_b = sm + 64 * 136;
  const int m0 = blockIdx.x * 64, n0 = blockIdx.y * 64;
  const int t = threadIdx.x;
  const int wave = t >> 6, lane = t & 63;
  const int m = lane & 15, quad = lane >> 4;
  const int sr = t >> 2, spart = t & 3;
  f32x4 acc[4] = {{0,0,0,0},{0,0,0,0},{0,0,0,0},{0,0,0,0}};
  for (int kc = 0; kc < 512; kc += 64) {
    #pragma unroll
    for (int it = 0; it < 2; ++it) {
      *(short8*)(s_a + sr * 136 + spart * 32 + it * 16) =
        *(const short8*)(A + (size_t)(m0 + sr) * 512 + kc + spart * 16 + it * 8);
      *(short8*)(s_b + sr * 136 + spart * 32 + it * 16) =
        *(const short8*)(Bt + (size_t)(n0 + sr) * 512 + kc + spart * 16 + it * 8);
    }
    __syncthreads();
    #pragma unroll
    for (int k2 = 0; k2 < 2; ++k2) {
      short8 af = *(const short8*)(s_a + (wave * 16 + m) * 136 + k2 * 64 + quad * 16);
      #pragma unroll
      for (int nt = 0; nt < 4; ++nt) {
        short8 bf = *(const short8*)(s_b + (nt * 16 + m) * 136 + k2 * 64 + quad * 16);
        acc[nt] = MFMA16(af, bf, acc[nt]);
      }
    }
    __syncthreads();
  }
  #pragma unroll
  for (int nt = 0; nt < 4; ++nt) {
    int col = n0 + nt * 16 + m;
    float bv = bias[col];
    #pragma unroll
    for (int r = 0; r < 4; ++r) {
      int row = m0 + wave * 16 + quad * 4 + r;
      C[(size_t)row * N + col] = acc[nt][r] + bv;
    }
  }
}

// ---------------- LN + activations -> Ub, Wb bf16 [h][i][128] ----------------
__global__ __launch_bounds__(256) void k_ln_act(const float* __restrict__ qs,
    const float* __restrict__ lnw, const float* __restrict__ lnb,
    const float* __restrict__ fr, const float* __restrict__ psh,
    unsigned short* __restrict__ Ub, unsigned short* __restrict__ Wb) {
  __shared__ float sred[12];
  const int i = blockIdx.x, t = threadIdx.x;
  const int wave = t >> 6, lane = t & 63;
  const float* row = qs + (size_t)i * 1024;
  float v0 = row[t], v1 = row[t + 256], v2 = row[t + 512], v3 = row[t + 768];
  float s = v0 + v1 + v2 + v3;
  float s2 = v0 * v0 + v1 * v1 + v2 * v2 + v3 * v3;
  #pragma unroll
  for (int off = 32; off; off >>= 1) {
    s += __shfl_down(s, off, 64);
    s2 += __shfl_down(s2, off, 64);
  }
  if (lane == 0) { sred[wave] = s; sred[4 + wave] = s2; }
  __syncthreads();
  s = sred[0] + sred[1] + sred[2] + sred[3];
  s2 = sred[4] + sred[5] + sred[6] + sred[7];
  float mu = s * (1.0f / 1024.0f);
  float var = s2 * (1.0f / 1024.0f) - mu * mu;
  float rstd = 1.0f / sqrtf(var + 1e-5f);
  float y0 = (v0 - mu) * rstd * lnw[t]       + lnb[t];
  float y1 = (v1 - mu) * rstd * lnw[t + 256] + lnb[t + 256];
  float y2 = (v2 - mu) * rstd * lnw[t + 512] + lnb[t + 512];
  float y3 = (v3 - mu) * rstd * lnw[t + 768] + lnb[t + 768];
  float a0 = 1.0f / (1.0f + __expf(-y0));
  float a1 = 1.0f / (1.0f + __expf(-y1));
  float na = a0 * a0 + a1 * a1;
  #pragma unroll
  for (int off = 32; off; off >>= 1) na += __shfl_down(na, off, 64);
  __syncthreads();                      // everyone done reading sred[0..7]
  if (lane == 0) sred[8 + wave] = na;
  __syncthreads();
  na = sred[8] + sred[9] + sred[10] + sred[11];
  float inv = 1.0f / (sqrtf(na) + 1e-8f);
  float af0 = a0 * inv, af1 = a1 * inv;
  const float PI_F = 3.14159265358979323846f;
  float p2 = tanhf(y2) * PI_F;          // phase for head h0
  float p3 = tanhf(y3) * PI_F;          // phase for head h0+4
  const double GAM = 1024.0 / 1023.0;   // table-step rescale (linspace endpoint)
  int h0 = t >> 6, d0 = t & 63, h1 = h0 + 4;
  float c10 = (float)((double)fr[h0] * GAM);
  float s10 = (float)((double)psh[h0] * GAM);
  float c11 = (float)((double)fr[h1] * GAM);
  float s11 = (float)((double)psh[h1] * GAM);
  float A0 = fmaf(p2, c10, s10), Bp0 = p2 * c10;
  float A1 = fmaf(p3, c11, s11), Bp1 = p3 * c11;
  float cA0, sA0, cB0, sB0, cA1, sA1, cB1, sB1;
  sincosf(A0, &sA0, &cA0);
  sincosf(Bp0, &sB0, &cB0);
  sincosf(A1, &sA1, &cA1);
  sincosf(Bp1, &sB1, &cB1);
  size_t b0 = ((size_t)h0 * 2048 + i) * 128 + d0;
  size_t b1 = ((size_t)h1 * 2048 + i) * 128 + d0;
  Ub[b0] = f2bf(af0 * cA0);  Ub[b0 + 64] = f2bf(af0 * sA0);
  Wb[b0] = f2bf(af0 * cB0);  Wb[b0 + 64] = f2bf(af0 * sB0);
  Ub[b1] = f2bf(af1 * cA1);  Ub[b1 + 64] = f2bf(af1 * sA1);
  Wb[b1] = f2bf(af1 * cB1);  Wb[b1 + 64] = f2bf(af1 * sB1);
}

// ---------------- fused MFMA flash: scores + softmax + PV (k-split 2) ----------------
__global__ __launch_bounds__(256, 2) void k_flash3(const unsigned short* __restrict__ Ub,
    const unsigned short* __restrict__ Wb, const unsigned short* __restrict__ vT,
    float* __restrict__ Opart, float* __restrict__ Dpart) {
  __shared__ __align__(16) unsigned char sm[35840];
  unsigned char* s_w = sm;             // 64 k-rows x 272B (128 bf16 + 16B pad)
  unsigned char* s_v = sm + 17408;     // 64 d-rows x 144B (64 bf16 + 16B pad)
  unsigned char* s_p = sm + 26624;     // 4 waves x 16 q x 144B
  const int qt = blockIdx.x, h = blockIdx.y, ks = blockIdx.z;
  const int q0 = qt * 64;
  const int t = threadIdx.x;
  const int wave = t >> 6, lane = t & 63;
  const int m = lane & 15, quad = lane >> 4;
  const int sr = t >> 2, spart = t & 3;
  unsigned char* s_pw = s_p + wave * 2304;
  // preload U A-frags (q-side, k-tile-invariant)
  short8 afr[4];
  const unsigned short* urow = Ub + ((size_t)h * 2048 + q0 + wave * 16 + m) * 128;
  #pragma unroll
  for (int fs = 0; fs < 4; ++fs)
    afr[fs] = *(const short8*)(urow + fs * 32 + quad * 8);
  short8 ones;
  #pragma unroll
  for (int j = 0; j < 8; ++j) ones[j] = (short)0x3F80;   // bf16 1.0
  f32x4 oacc[4] = {{0,0,0,0},{0,0,0,0},{0,0,0,0},{0,0,0,0}};
  f32x4 dacc = {0, 0, 0, 0};
  for (int kt = 0; kt < 16; ++kt) {
    const int k0 = ks * 1024 + kt * 64;
    // stage W-tile (16KB) + V-tile (8KB), padded strides
    const unsigned short* wg = Wb + ((size_t)h * 2048 + k0) * 128;
    #pragma unroll
    for (int it = 0; it < 4; ++it)
      *(short8*)(s_w + sr * 272 + spart * 64 + it * 16) =
        *(const short8*)(wg + sr * 128 + spart * 32 + it * 8);
    const unsigned short* vg = vT + ((size_t)h * 64 + sr) * 2048 + k0;
    #pragma unroll
    for (int it = 0; it < 2; ++it)
      *(short8*)(s_v + sr * 144 + spart * 32 + it * 16) =
        *(const short8*)(vg + spart * 16 + it * 8);
    __syncthreads();
    // scores: S[16q x 64k] per wave = 4 ksub-tiles x 4 f-steps
    f32x4 sc[4] = {{0,0,0,0},{0,0,0,0},{0,0,0,0},{0,0,0,0}};
    #pragma unroll
    for (int ksub = 0; ksub < 4; ++ksub)
      #pragma unroll
      for (int fs = 0; fs < 4; ++fs) {
        short8 bfr = *(const short8*)(s_w + (ksub * 16 + m) * 272 + fs * 64 + quad * 16);
        sc[ksub] = MFMA16(afr[fs], bfr, sc[ksub]);
      }
    // p = exp(S/8) -> LDS bf16 in [q][j] (C-layout write, A-layout re-read)
    #pragma unroll
    for (int ksub = 0; ksub < 4; ++ksub)
      #pragma unroll
      for (int r = 0; r < 4; ++r) {
        float p = __expf(sc[ksub][r] * 0.125f);
        *(unsigned short*)(s_pw + (quad * 4 + r) * 144 + (ksub * 16 + m) * 2) = f2bf(p);
      }
    __syncthreads();
    // PV + den via MFMA
    #pragma unroll
    for (int k2 = 0; k2 < 2; ++k2) {
      short8 pf = *(const short8*)(s_pw + m * 144 + k2 * 64 + quad * 16);
      dacc = MFMA16(pf, ones, dacc);
      #pragma unroll
      for (int dt = 0; dt < 4; ++dt) {
        short8 vf = *(const short8*)(s_v + (dt * 16 + m) * 144 + k2 * 64 + quad * 16);
        oacc[dt] = MFMA16(pf, vf, oacc[dt]);
      }
    }
    __syncthreads();
  }
  // write unnormalized partials
  const size_t obase = (((size_t)ks * 8 + h) * 2048 + q0 + wave * 16) * 64;
  #pragma unroll
  for (int dt = 0; dt < 4; ++dt)
    #pragma unroll
    for (int r = 0; r < 4; ++r)
      Opart[obase + (size_t)(quad * 4 + r) * 64 + dt * 16 + m] = oacc[dt][r];
  if (m == 0) {
    #pragma unroll
    for (int r = 0; r < 4; ++r)
      Dpart[((size_t)ks * 8 + h) * 2048 + q0 + wave * 16 + quad * 4 + r] = dacc[r];
  }
}

// ---------------- combine k-split partials -> att bf16 [2048][512] ----------------
__global__ __launch_bounds__(256) void k_combine(const float* __restrict__ Opart,
    const float* __restrict__ Dpart, unsigned short* __restrict__ attb) {
  int n = blockIdx.x * 256 + threadIdx.x;      // over 2048*512
  int q = n >> 9, c = n & 511;
  int h = c >> 6, d = c & 63;
  size_t i0 = (((size_t)h) * 2048 + q) * 64 + d;
  size_t i1 = (((size_t)8 + h) * 2048 + q) * 64 + d;
  float o = Opart[i0] + Opart[i1];
  float den = Dpart[h * 2048 + q] + Dpart[8 * 2048 + h * 2048 + q];
  attb[n] = f2bf(o / den);
}

extern "C" void kernel_launch(void* const* d_in, const int* in_sizes, int n_in,
                              void* d_out, int out_size, void* d_ws, size_t ws_size,
                              hipStream_t stream) {
  (void)in_sizes; (void)n_in; (void)out_size; (void)ws_size;
  const float* x   = (const float*)d_in[0];
  const float* Wq  = (const float*)d_in[1];
  const float* bq  = (const float*)d_in[2];
  const float* lnw = (const float*)d_in[3];
  const float* lnb = (const float*)d_in[4];
  const float* fr  = (const float*)d_in[5];
  const float* ps  = (const float*)d_in[6];
  const float* Wo  = (const float*)d_in[7];
  const float* bo  = (const float*)d_in[8];
  // d_in[9] = cos_table: unused (smooth-cos factorization)
  char* ws = (char*)d_ws;
  float*          qs    = (float*)(ws + B_QS);
  float*          Opart = (float*)(ws + B_OP);
  float*          Dpart = (float*)(ws + B_DP);
  unsigned short* Ub    = (unsigned short*)(ws + B_UB);
  unsigned short* Wb    = (unsigned short*)(ws + B_WB);
  unsigned short* xb    = (unsigned short*)(ws + B_XB);
  unsigned short* vT    = (unsigned short*)(ws + B_VT);
  unsigned short* WqT   = (unsigned short*)(ws + B_WQT);
  unsigned short* WoT   = (unsigned short*)(ws + B_WOT);
  unsigned short* attb  = (unsigned short*)(ws + B_ATTB);
  float* out = (float*)d_out;

  k_cast_x<<<dim3(32, 8), 256, 0, stream>>>(x, xb, vT);
  k_cast_w<<<192, 256, 0, stream>>>(Wq, Wo, WqT, WoT);
  k_gemm<<<dim3(32, 16), 256, 0, stream>>>(xb, WqT, bq, qs, 1024);
  k_ln_act<<<2048, 256, 0, stream>>>(qs, lnw, lnb, fr, ps, Ub, Wb);
  k_flash3<<<dim3(32, 8, 2), 256, 0, stream>>>(Ub, Wb, vT, Opart, Dpart);
  k_combine<<<4096, 256, 0, stream>>>(Opart, Dpart, attb);
  k_gemm<<<dim3(32, 8), 256, 0, stream>>>(attb, WoT, bo, out, 512);
}

// Round 5
// 160.569 us; speedup vs baseline: 4.6592x; 1.0467x over previous
//
#include <hip/hip_runtime.h>
#include <cstdint>
#include <cstddef>

// B=1, L=2048, DIM=512, H=8, D=64, STEPS=1024.  R5: all-MFMA pipeline (bf16).
// R5 changes vs R4:
//  - k_prep: merged cast_x + cast_w (one dispatch fewer)
//  - k_ln_act: fast transcendentals (__expf-based tanh, __sincosf) - libm
//    sincosf/tanhf were ~1600 VALU cyc/thread
//  - k_flash4: double-buffered W/V staging -> 2 barriers/kt (was 3), global
//    loads issued before the MFMA phase so HBM/L2 latency overlaps compute
//  - k_out_gemm: combine fused into A-staging (normalize Opart by den while
//    building bf16 A-fragments); k_combine and attb eliminated
//
//  pipeline: k_prep -> k_gemm(qs) -> k_ln_act -> k_flash4 -> k_out_gemm

typedef __attribute__((ext_vector_type(8))) short short8;
typedef __attribute__((ext_vector_type(4))) float f32x4;

#define MFMA16(a, b, c) __builtin_amdgcn_mfma_f32_16x16x32_bf16((a), (b), (c), 0, 0, 0)

static constexpr size_t B_QS   = 0;
static constexpr size_t B_OP   = 0;                       // Opart reuses qs
static constexpr size_t B_DP   = (size_t)8 * 1024 * 1024;
static constexpr size_t B_UB   = B_DP + 256 * 1024;
static constexpr size_t B_WB   = B_UB + (size_t)4 * 1024 * 1024;
static constexpr size_t B_XB   = B_WB + (size_t)4 * 1024 * 1024;
static constexpr size_t B_VT   = B_XB + (size_t)2 * 1024 * 1024;
static constexpr size_t B_WQT  = B_VT + (size_t)2 * 1024 * 1024;
static constexpr size_t B_WOT  = B_WQT + (size_t)1 * 1024 * 1024;

__device__ __forceinline__ unsigned short f2bf(float f) {
  unsigned u = __float_as_uint(f);
  return (unsigned short)((u + 0x7FFFu + ((u >> 16) & 1u)) >> 16);
}

// ---------------- prep: cast x -> xb,vT  and  Wq/Wo -> WqT/WoT ----------------
__global__ __launch_bounds__(256) void k_prep(const float* __restrict__ x,
    const float* __restrict__ Wq, const float* __restrict__ Wo,
    unsigned short* __restrict__ xb, unsigned short* __restrict__ vT,
    unsigned short* __restrict__ WqT, unsigned short* __restrict__ WoT) {
  __shared__ float tl[64 * 65];
  const int t = threadIdx.x;
  const int b = blockIdx.x;
  if (b < 256) {
    // cast_x: block per (64-row tile, head)
    const int i0 = (b >> 3) * 64, h = b & 7;
    #pragma unroll
    for (int it = 0; it < 16; ++it) {
      int n = t + 256 * it;
      int r = n >> 6, c = n & 63;
      float v = x[(size_t)(i0 + r) * 512 + h * 64 + c];
      tl[r * 65 + c] = v;
      xb[(size_t)(i0 + r) * 512 + h * 64 + c] = f2bf(v);
    }
    __syncthreads();
    #pragma unroll
    for (int it = 0; it < 16; ++it) {
      int n = t + 256 * it;
      int d = n >> 6, ii = n & 63;
      vT[(size_t)(h * 64 + d) * 2048 + i0 + ii] = f2bf(tl[ii * 65 + d]);
    }
  } else {
    int bb = b - 256;
    const float* src; unsigned short* dst; int k0, n0, N;
    if (bb < 128) { src = Wq; dst = WqT; k0 = (bb >> 4) * 64; n0 = (bb & 15) * 64; N = 1024; }
    else { bb -= 128; src = Wo; dst = WoT; k0 = (bb >> 3) * 64; n0 = (bb & 7) * 64; N = 512; }
    #pragma unroll
    for (int it = 0; it < 16; ++it) {
      int n = t + 256 * it;
      int r = n >> 6, c = n & 63;
      tl[r * 65 + c] = src[(size_t)(k0 + r) * N + n0 + c];
    }
    __syncthreads();
    #pragma unroll
    for (int it = 0; it < 16; ++it) {
      int n = t + 256 * it;
      int rr = n >> 6, cc = n & 63;
      dst[(size_t)(n0 + rr) * 512 + k0 + cc] = f2bf(tl[cc * 65 + rr]);
    }
  }
}

// ---------------- qs GEMM: C[M][1024] = A[M][512] @ Bt[1024][512]^T + bias ----
__global__ __launch_bounds__(256) void k_gemm(const unsigned short* __restrict__ A,
    const unsigned short* __restrict__ Bt, const float* __restrict__ bias,
    float* __restrict__ C, int N) {
  __shared__ __align__(16) unsigned char sm[2 * 64 * 136];
  unsigned char* s_a = sm;
  unsigned char* s_b = sm + 64 * 136;
  const int m0 = blockIdx.x * 64, n0 = blockIdx.y * 64;
  const int t = threadIdx.x;
  const int wave = t >> 6, lane = t & 63;
  const int m = lane & 15, quad = lane >> 4;
  const int sr = t >> 2, spart = t & 3;
  f32x4 acc[4] = {{0,0,0,0},{0,0,0,0},{0,0,0,0},{0,0,0,0}};
  for (int kc = 0; kc < 512; kc += 64) {
    #pragma unroll
    for (int it = 0; it < 2; ++it) {
      *(short8*)(s_a + sr * 136 + spart * 32 + it * 16) =
        *(const short8*)(A + (size_t)(m0 + sr) * 512 + kc + spart * 16 + it * 8);
      *(short8*)(s_b + sr * 136 + spart * 32 + it * 16) =
        *(const short8*)(Bt + (size_t)(n0 + sr) * 512 + kc + spart * 16 + it * 8);
    }
    __syncthreads();
    #pragma unroll
    for (int k2 = 0; k2 < 2; ++k2) {
      short8 af = *(const short8*)(s_a + (wave * 16 + m) * 136 + k2 * 64 + quad * 16);
      #pragma unroll
      for (int nt = 0; nt < 4; ++nt) {
        short8 bf = *(const short8*)(s_b + (nt * 16 + m) * 136 + k2 * 64 + quad * 16);
        acc[nt] = MFMA16(af, bf, acc[nt]);
      }
    }
    __syncthreads();
  }
  #pragma unroll
  for (int nt = 0; nt < 4; ++nt) {
    int col = n0 + nt * 16 + m;
    float bv = bias[col];
    #pragma unroll
    for (int r = 0; r < 4; ++r) {
      int row = m0 + wave * 16 + quad * 4 + r;
      C[(size_t)row * N + col] = acc[nt][r] + bv;
    }
  }
}

// ---------------- LN + activations -> Ub, Wb bf16 [h][i][128] ----------------
__global__ __launch_bounds__(256) void k_ln_act(const float* __restrict__ qs,
    const float* __restrict__ lnw, const float* __restrict__ lnb,
    const float* __restrict__ fr, const float* __restrict__ psh,
    unsigned short* __restrict__ Ub, unsigned short* __restrict__ Wb) {
  __shared__ float sred[12];
  const int i = blockIdx.x, t = threadIdx.x;
  const int wave = t >> 6, lane = t & 63;
  const float* row = qs + (size_t)i * 1024;
  float v0 = row[t], v1 = row[t + 256], v2 = row[t + 512], v3 = row[t + 768];
  float s = v0 + v1 + v2 + v3;
  float s2 = v0 * v0 + v1 * v1 + v2 * v2 + v3 * v3;
  #pragma unroll
  for (int off = 32; off; off >>= 1) {
    s += __shfl_down(s, off, 64);
    s2 += __shfl_down(s2, off, 64);
  }
  if (lane == 0) { sred[wave] = s; sred[4 + wave] = s2; }
  __syncthreads();
  s = sred[0] + sred[1] + sred[2] + sred[3];
  s2 = sred[4] + sred[5] + sred[6] + sred[7];
  float mu = s * (1.0f / 1024.0f);
  float var = s2 * (1.0f / 1024.0f) - mu * mu;
  float rstd = 1.0f / sqrtf(var + 1e-5f);
  float y0 = (v0 - mu) * rstd * lnw[t]       + lnb[t];
  float y1 = (v1 - mu) * rstd * lnw[t + 256] + lnb[t + 256];
  float y2 = (v2 - mu) * rstd * lnw[t + 512] + lnb[t + 512];
  float y3 = (v3 - mu) * rstd * lnw[t + 768] + lnb[t + 768];
  float a0 = __builtin_amdgcn_rcpf(1.0f + __expf(-y0));
  float a1 = __builtin_amdgcn_rcpf(1.0f + __expf(-y1));
  float na = a0 * a0 + a1 * a1;
  #pragma unroll
  for (int off = 32; off; off >>= 1) na += __shfl_down(na, off, 64);
  __syncthreads();
  if (lane == 0) sred[8 + wave] = na;
  __syncthreads();
  na = sred[8] + sred[9] + sred[10] + sred[11];
  float inv = 1.0f / (sqrtf(na) + 1e-8f);
  float af0 = a0 * inv, af1 = a1 * inv;
  const float PI_F = 3.14159265358979323846f;
  // fast tanh: 1 - 2/(e^{2y}+1); exact at +-inf, ~1e-7 rel error
  float e2a = __expf(2.0f * y2);
  float e2b = __expf(2.0f * y3);
  float p2 = (1.0f - 2.0f * __builtin_amdgcn_rcpf(e2a + 1.0f)) * PI_F;
  float p3 = (1.0f - 2.0f * __builtin_amdgcn_rcpf(e2b + 1.0f)) * PI_F;
  const double GAM = 1024.0 / 1023.0;   // table-step rescale (linspace endpoint)
  int h0 = t >> 6, d0 = t & 63, h1 = h0 + 4;
  float c10 = (float)((double)fr[h0] * GAM);
  float s10 = (float)((double)psh[h0] * GAM);
  float c11 = (float)((double)fr[h1] * GAM);
  float s11 = (float)((double)psh[h1] * GAM);
  float A0 = fmaf(p2, c10, s10), Bp0 = p2 * c10;
  float A1 = fmaf(p3, c11, s11), Bp1 = p3 * c11;
  float cA0, sA0, cB0, sB0, cA1, sA1, cB1, sB1;
  __sincosf(A0, &sA0, &cA0);    // |args| < 0.5 rad; abs err ~5e-7 << bf16 round
  __sincosf(Bp0, &sB0, &cB0);
  __sincosf(A1, &sA1, &cA1);
  __sincosf(Bp1, &sB1, &cB1);
  size_t b0 = ((size_t)h0 * 2048 + i) * 128 + d0;
  size_t b1 = ((size_t)h1 * 2048 + i) * 128 + d0;
  Ub[b0] = f2bf(af0 * cA0);  Ub[b0 + 64] = f2bf(af0 * sA0);
  Wb[b0] = f2bf(af0 * cB0);  Wb[b0 + 64] = f2bf(af0 * sB0);
  Ub[b1] = f2bf(af1 * cA1);  Ub[b1 + 64] = f2bf(af1 * sA1);
  Wb[b1] = f2bf(af1 * cB1);  Wb[b1 + 64] = f2bf(af1 * sB1);
}

// ---------------- fused MFMA flash, double-buffered staging (k-split 2) --------
__global__ __launch_bounds__(256, 2) void k_flash4(const unsigned short* __restrict__ Ub,
    const unsigned short* __restrict__ Wb, const unsigned short* __restrict__ vT,
    float* __restrict__ Opart, float* __restrict__ Dpart) {
  __shared__ __align__(16) unsigned char s_w[2][64 * 272];  // [k 64][f 128 bf16 + pad]
  __shared__ __align__(16) unsigned char s_v[2][64 * 144];  // [d 64][k 64 bf16 + pad]
  __shared__ __align__(16) unsigned char s_p[4][16 * 144];  // per wave [q 16][k 64 + pad]
  const int qt = blockIdx.x, h = blockIdx.y, ks = blockIdx.z;
  const int q0 = qt * 64;
  const int t = threadIdx.x;
  const int wave = t >> 6, lane = t & 63;
  const int m = lane & 15, quad = lane >> 4;
  const int sr = t >> 2, spart = t & 3;
  unsigned char* s_pw = s_p[wave];
  // preload U A-frags (q-side, k-tile-invariant)
  short8 afr[4];
  const unsigned short* urow = Ub + ((size_t)h * 2048 + q0 + wave * 16 + m) * 128;
  #pragma unroll
  for (int fs = 0; fs < 4; ++fs)
    afr[fs] = *(const short8*)(urow + fs * 32 + quad * 8);
  short8 ones;
  #pragma unroll
  for (int j = 0; j < 8; ++j) ones[j] = (short)0x3F80;   // bf16 1.0
  f32x4 oacc[4] = {{0,0,0,0},{0,0,0,0},{0,0,0,0},{0,0,0,0}};
  f32x4 dacc = {0, 0, 0, 0};
  const unsigned short* wgbase = Wb + ((size_t)h * 2048 + ks * 1024) * 128 + (size_t)sr * 128;
  const unsigned short* vgbase = vT + ((size_t)h * 64 + sr) * 2048 + ks * 1024;
  // prologue: stage kt=0 into buffer 0
  #pragma unroll
  for (int it = 0; it < 4; ++it)
    *(short8*)(s_w[0] + sr * 272 + spart * 64 + it * 16) =
      *(const short8*)(wgbase + spart * 32 + it * 8);
  #pragma unroll
  for (int it = 0; it < 2; ++it)
    *(short8*)(s_v[0] + sr * 144 + spart * 32 + it * 16) =
      *(const short8*)(vgbase + spart * 16 + it * 8);
  __syncthreads();
  for (int kt = 0; kt < 16; ++kt) {
    const int cur = kt & 1;
    // issue next k-tile's global loads first (latency overlaps MFMA below)
    short8 wst[4], vst[2];
    const bool has = (kt < 15);
    if (has) {
      const unsigned short* wg = wgbase + (size_t)(kt + 1) * 64 * 128;
      #pragma unroll
      for (int it = 0; it < 4; ++it)
        wst[it] = *(const short8*)(wg + spart * 32 + it * 8);
      const unsigned short* vg = vgbase + (kt + 1) * 64;
      #pragma unroll
      for (int it = 0; it < 2; ++it)
        vst[it] = *(const short8*)(vg + spart * 16 + it * 8);
    }
    // scores: S[16q x 64k] per wave
    f32x4 sc[4] = {{0,0,0,0},{0,0,0,0},{0,0,0,0},{0,0,0,0}};
    #pragma unroll
    for (int ksub = 0; ksub < 4; ++ksub)
      #pragma unroll
      for (int fs = 0; fs < 4; ++fs) {
        short8 bfr = *(const short8*)(s_w[cur] + (ksub * 16 + m) * 272 + fs * 64 + quad * 16);
        sc[ksub] = MFMA16(afr[fs], bfr, sc[ksub]);
      }
    // p = exp(S/8) -> per-wave LDS region (C-layout write, A-layout re-read)
    #pragma unroll
    for (int ksub = 0; ksub < 4; ++ksub)
      #pragma unroll
      for (int r = 0; r < 4; ++r) {
        float p = __expf(sc[ksub][r] * 0.125f);
        *(unsigned short*)(s_pw + (quad * 4 + r) * 144 + (ksub * 16 + m) * 2) = f2bf(p);
      }
    // commit staged tile to the other buffer
    if (has) {
      #pragma unroll
      for (int it = 0; it < 4; ++it)
        *(short8*)(s_w[cur ^ 1] + sr * 272 + spart * 64 + it * 16) = wst[it];
      #pragma unroll
      for (int it = 0; it < 2; ++it)
        *(short8*)(s_v[cur ^ 1] + sr * 144 + spart * 32 + it * 16) = vst[it];
    }
    __syncthreads();
    // PV + den via MFMA
    #pragma unroll
    for (int k2 = 0; k2 < 2; ++k2) {
      short8 pf = *(const short8*)(s_pw + m * 144 + k2 * 64 + quad * 16);
      dacc = MFMA16(pf, ones, dacc);
      #pragma unroll
      for (int dt = 0; dt < 4; ++dt) {
        short8 vf = *(const short8*)(s_v[cur] + (dt * 16 + m) * 144 + k2 * 64 + quad * 16);
        oacc[dt] = MFMA16(pf, vf, oacc[dt]);
      }
    }
    __syncthreads();
  }
  // write unnormalized partials
  const size_t obase = (((size_t)ks * 8 + h) * 2048 + q0 + wave * 16) * 64;
  #pragma unroll
  for (int dt = 0; dt < 4; ++dt)
    #pragma unroll
    for (int r = 0; r < 4; ++r)
      Opart[obase + (size_t)(quad * 4 + r) * 64 + dt * 16 + m] = oacc[dt][r];
  if (m == 0) {
    #pragma unroll
    for (int r = 0; r < 4; ++r)
      Dpart[((size_t)ks * 8 + h) * 2048 + q0 + wave * 16 + quad * 4 + r] = dacc[r];
  }
}

// ------- out GEMM with fused combine: A = (O0+O1)/(den0+den1) cast bf16 -------
__global__ __launch_bounds__(256) void k_out_gemm(const float* __restrict__ Opart,
    const float* __restrict__ Dpart, const unsigned short* __restrict__ WoT,
    const float* __restrict__ bo, float* __restrict__ out) {
  __shared__ __align__(16) unsigned char sm[2 * 64 * 136];
  unsigned char* s_a = sm;
  unsigned char* s_b = sm + 64 * 136;
  const int m0 = blockIdx.x * 64, n0 = blockIdx.y * 64;
  const int t = threadIdx.x;
  const int wave = t >> 6, lane = t & 63;
  const int m = lane & 15, quad = lane >> 4;
  const int sr = t >> 2, spart = t & 3;
  f32x4 acc[4] = {{0,0,0,0},{0,0,0,0},{0,0,0,0},{0,0,0,0}};
  for (int kc = 0; kc < 512; kc += 64) {
    const int h = kc >> 6;
    const int row = m0 + sr;
    float invd = 1.0f / (Dpart[(size_t)h * 2048 + row] +
                         Dpart[(size_t)(8 + h) * 2048 + row]);
    const float* o0 = Opart + ((size_t)h * 2048 + row) * 64 + spart * 16;
    const float* o1 = Opart + ((size_t)(8 + h) * 2048 + row) * 64 + spart * 16;
    unsigned short ab[16];
    #pragma unroll
    for (int it = 0; it < 4; ++it) {
      f32x4 a0 = *(const f32x4*)(o0 + it * 4);
      f32x4 a1 = *(const f32x4*)(o1 + it * 4);
      #pragma unroll
      for (int j = 0; j < 4; ++j)
        ab[it * 4 + j] = f2bf((a0[j] + a1[j]) * invd);
    }
    *(short8*)(s_a + sr * 136 + spart * 32)      = *(short8*)(ab);
    *(short8*)(s_a + sr * 136 + spart * 32 + 16) = *(short8*)(ab + 8);
    #pragma unroll
    for (int it = 0; it < 2; ++it)
      *(short8*)(s_b + sr * 136 + spart * 32 + it * 16) =
        *(const short8*)(WoT + (size_t)(n0 + sr) * 512 + kc + spart * 16 + it * 8);
    __syncthreads();
    #pragma unroll
    for (int k2 = 0; k2 < 2; ++k2) {
      short8 af = *(const short8*)(s_a + (wave * 16 + m) * 136 + k2 * 64 + quad * 16);
      #pragma unroll
      for (int nt = 0; nt < 4; ++nt) {
        short8 bf = *(const short8*)(s_b + (nt * 16 + m) * 136 + k2 * 64 + quad * 16);
        acc[nt] = MFMA16(af, bf, acc[nt]);
      }
    }
    __syncthreads();
  }
  #pragma unroll
  for (int nt = 0; nt < 4; ++nt) {
    int col = n0 + nt * 16 + m;
    float bv = bo[col];
    #pragma unroll
    for (int r = 0; r < 4; ++r) {
      int row = m0 + wave * 16 + quad * 4 + r;
      out[(size_t)row * 512 + col] = acc[nt][r] + bv;
    }
  }
}

extern "C" void kernel_launch(void* const* d_in, const int* in_sizes, int n_in,
                              void* d_out, int out_size, void* d_ws, size_t ws_size,
                              hipStream_t stream) {
  (void)in_sizes; (void)n_in; (void)out_size; (void)ws_size;
  const float* x   = (const float*)d_in[0];
  const float* Wq  = (const float*)d_in[1];
  const float* bq  = (const float*)d_in[2];
  const float* lnw = (const float*)d_in[3];
  const float* lnb = (const float*)d_in[4];
  const float* fr  = (const float*)d_in[5];
  const float* ps  = (const float*)d_in[6];
  const float* Wo  = (const float*)d_in[7];
  const float* bo  = (const float*)d_in[8];
  // d_in[9] = cos_table: unused (smooth-cos factorization)
  char* ws = (char*)d_ws;
  float*          qs    = (float*)(ws + B_QS);
  float*          Opart = (float*)(ws + B_OP);
  float*          Dpart = (float*)(ws + B_DP);
  unsigned short* Ub    = (unsigned short*)(ws + B_UB);
  unsigned short* Wb    = (unsigned short*)(ws + B_WB);
  unsigned short* xb    = (unsigned short*)(ws + B_XB);
  unsigned short* vT    = (unsigned short*)(ws + B_VT);
  unsigned short* WqT   = (unsigned short*)(ws + B_WQT);
  unsigned short* WoT   = (unsigned short*)(ws + B_WOT);
  float* out = (float*)d_out;

  k_prep<<<448, 256, 0, stream>>>(x, Wq, Wo, xb, vT, WqT, WoT);
  k_gemm<<<dim3(32, 16), 256, 0, stream>>>(xb, WqT, bq, qs, 1024);
  k_ln_act<<<2048, 256, 0, stream>>>(qs, lnw, lnb, fr, ps, Ub, Wb);
  k_flash4<<<dim3(32, 8, 2), 256, 0, stream>>>(Ub, Wb, vT, Opart, Dpart);
  k_out_gemm<<<dim3(32, 8), 256, 0, stream>>>(Opart, Dpart, WoT, bo, out);
}

// Round 6
// 155.969 us; speedup vs baseline: 4.7965x; 1.0295x over previous
//
#include <hip/hip_runtime.h>
#include <cstdint>
#include <cstddef>

// B=1, L=2048, DIM=512, H=8, D=64, STEPS=1024.  R6: all-MFMA pipeline (bf16).
// R6 change: flash5 owns full k (no k-split): 512-thread blocks, 8 waves =
// (4 q-groups) x (2 k-halves) over 128-k double-buffered tiles; O/den halves
// combined in LDS at end, normalized, written as bf16 attb directly.
// Opart/Dpart (16 MB fp32 write + 64 MB re-read in the out-GEMM) eliminated;
// out-GEMM is now the plain bf16 k_gemm on attb (2 MB).
//
//  pipeline: k_prep -> k_gemm(qs) -> k_ln_act -> k_flash5 -> k_gemm(out)

typedef __attribute__((ext_vector_type(8))) short short8;
typedef __attribute__((ext_vector_type(4))) float f32x4;

#define MFMA16(a, b, c) __builtin_amdgcn_mfma_f32_16x16x32_bf16((a), (b), (c), 0, 0, 0)

static constexpr size_t B_QS   = 0;                       // f32 [2048][1024] = 8 MB
static constexpr size_t B_ATTB = 0;                       // bf16 [2048][512], reuses qs
static constexpr size_t B_UB   = (size_t)8 * 1024 * 1024;
static constexpr size_t B_WB   = B_UB + (size_t)4 * 1024 * 1024;
static constexpr size_t B_XB   = B_WB + (size_t)4 * 1024 * 1024;
static constexpr size_t B_VT   = B_XB + (size_t)2 * 1024 * 1024;
static constexpr size_t B_WQT  = B_VT + (size_t)2 * 1024 * 1024;
static constexpr size_t B_WOT  = B_WQT + (size_t)1 * 1024 * 1024;

__device__ __forceinline__ unsigned short f2bf(float f) {
  unsigned u = __float_as_uint(f);
  return (unsigned short)((u + 0x7FFFu + ((u >> 16) & 1u)) >> 16);
}

// ---------------- prep: cast x -> xb,vT  and  Wq/Wo -> WqT/WoT ----------------
__global__ __launch_bounds__(256) void k_prep(const float* __restrict__ x,
    const float* __restrict__ Wq, const float* __restrict__ Wo,
    unsigned short* __restrict__ xb, unsigned short* __restrict__ vT,
    unsigned short* __restrict__ WqT, unsigned short* __restrict__ WoT) {
  __shared__ float tl[64 * 65];
  const int t = threadIdx.x;
  const int b = blockIdx.x;
  if (b < 256) {
    const int i0 = (b >> 3) * 64, h = b & 7;
    #pragma unroll
    for (int it = 0; it < 16; ++it) {
      int n = t + 256 * it;
      int r = n >> 6, c = n & 63;
      float v = x[(size_t)(i0 + r) * 512 + h * 64 + c];
      tl[r * 65 + c] = v;
      xb[(size_t)(i0 + r) * 512 + h * 64 + c] = f2bf(v);
    }
    __syncthreads();
    #pragma unroll
    for (int it = 0; it < 16; ++it) {
      int n = t + 256 * it;
      int d = n >> 6, ii = n & 63;
      vT[(size_t)(h * 64 + d) * 2048 + i0 + ii] = f2bf(tl[ii * 65 + d]);
    }
  } else {
    int bb = b - 256;
    const float* src; unsigned short* dst; int k0, n0, N;
    if (bb < 128) { src = Wq; dst = WqT; k0 = (bb >> 4) * 64; n0 = (bb & 15) * 64; N = 1024; }
    else { bb -= 128; src = Wo; dst = WoT; k0 = (bb >> 3) * 64; n0 = (bb & 7) * 64; N = 512; }
    #pragma unroll
    for (int it = 0; it < 16; ++it) {
      int n = t + 256 * it;
      int r = n >> 6, c = n & 63;
      tl[r * 65 + c] = src[(size_t)(k0 + r) * N + n0 + c];
    }
    __syncthreads();
    #pragma unroll
    for (int it = 0; it < 16; ++it) {
      int n = t + 256 * it;
      int rr = n >> 6, cc = n & 63;
      dst[(size_t)(n0 + rr) * 512 + k0 + cc] = f2bf(tl[cc * 65 + rr]);
    }
  }
}

// ------- generic bf16 MFMA GEMM: C[M][N] f32 = A[M][512] @ Bt[N][512]^T + bias ----
__global__ __launch_bounds__(256) void k_gemm(const unsigned short* __restrict__ A,
    const unsigned short* __restrict__ Bt, const float* __restrict__ bias,
    float* __restrict__ C, int N) {
  __shared__ __align__(16) unsigned char sm[2 * 64 * 136];
  unsigned char* s_a = sm;
  unsigned char* s_b = sm + 64 * 136;
  const int m0 = blockIdx.x * 64, n0 = blockIdx.y * 64;
  const int t = threadIdx.x;
  const int wave = t >> 6, lane = t & 63;
  const int m = lane & 15, quad = lane >> 4;
  const int sr = t >> 2, spart = t & 3;
  f32x4 acc[4] = {{0,0,0,0},{0,0,0,0},{0,0,0,0},{0,0,0,0}};
  for (int kc = 0; kc < 512; kc += 64) {
    #pragma unroll
    for (int it = 0; it < 2; ++it) {
      *(short8*)(s_a + sr * 136 + spart * 32 + it * 16) =
        *(const short8*)(A + (size_t)(m0 + sr) * 512 + kc + spart * 16 + it * 8);
      *(short8*)(s_b + sr * 136 + spart * 32 + it * 16) =
        *(const short8*)(Bt + (size_t)(n0 + sr) * 512 + kc + spart * 16 + it * 8);
    }
    __syncthreads();
    #pragma unroll
    for (int k2 = 0; k2 < 2; ++k2) {
      short8 af = *(const short8*)(s_a + (wave * 16 + m) * 136 + k2 * 64 + quad * 16);
      #pragma unroll
      for (int nt = 0; nt < 4; ++nt) {
        short8 bf = *(const short8*)(s_b + (nt * 16 + m) * 136 + k2 * 64 + quad * 16);
        acc[nt] = MFMA16(af, bf, acc[nt]);
      }
    }
    __syncthreads();
  }
  #pragma unroll
  for (int nt = 0; nt < 4; ++nt) {
    int col = n0 + nt * 16 + m;
    float bv = bias[col];
    #pragma unroll
    for (int r = 0; r < 4; ++r) {
      int row = m0 + wave * 16 + quad * 4 + r;
      C[(size_t)row * N + col] = acc[nt][r] + bv;
    }
  }
}

// ---------------- LN + activations -> Ub, Wb bf16 [h][i][128] ----------------
__global__ __launch_bounds__(256) void k_ln_act(const float* __restrict__ qs,
    const float* __restrict__ lnw, const float* __restrict__ lnb,
    const float* __restrict__ fr, const float* __restrict__ psh,
    unsigned short* __restrict__ Ub, unsigned short* __restrict__ Wb) {
  __shared__ float sred[12];
  const int i = blockIdx.x, t = threadIdx.x;
  const int wave = t >> 6, lane = t & 63;
  const float* row = qs + (size_t)i * 1024;
  float v0 = row[t], v1 = row[t + 256], v2 = row[t + 512], v3 = row[t + 768];
  float s = v0 + v1 + v2 + v3;
  float s2 = v0 * v0 + v1 * v1 + v2 * v2 + v3 * v3;
  #pragma unroll
  for (int off = 32; off; off >>= 1) {
    s += __shfl_down(s, off, 64);
    s2 += __shfl_down(s2, off, 64);
  }
  if (lane == 0) { sred[wave] = s; sred[4 + wave] = s2; }
  __syncthreads();
  s = sred[0] + sred[1] + sred[2] + sred[3];
  s2 = sred[4] + sred[5] + sred[6] + sred[7];
  float mu = s * (1.0f / 1024.0f);
  float var = s2 * (1.0f / 1024.0f) - mu * mu;
  float rstd = 1.0f / sqrtf(var + 1e-5f);
  float y0 = (v0 - mu) * rstd * lnw[t]       + lnb[t];
  float y1 = (v1 - mu) * rstd * lnw[t + 256] + lnb[t + 256];
  float y2 = (v2 - mu) * rstd * lnw[t + 512] + lnb[t + 512];
  float y3 = (v3 - mu) * rstd * lnw[t + 768] + lnb[t + 768];
  float a0 = __builtin_amdgcn_rcpf(1.0f + __expf(-y0));
  float a1 = __builtin_amdgcn_rcpf(1.0f + __expf(-y1));
  float na = a0 * a0 + a1 * a1;
  #pragma unroll
  for (int off = 32; off; off >>= 1) na += __shfl_down(na, off, 64);
  __syncthreads();
  if (lane == 0) sred[8 + wave] = na;
  __syncthreads();
  na = sred[8] + sred[9] + sred[10] + sred[11];
  float inv = 1.0f / (sqrtf(na) + 1e-8f);
  float af0 = a0 * inv, af1 = a1 * inv;
  const float PI_F = 3.14159265358979323846f;
  float e2a = __expf(2.0f * y2);
  float e2b = __expf(2.0f * y3);
  float p2 = (1.0f - 2.0f * __builtin_amdgcn_rcpf(e2a + 1.0f)) * PI_F;
  float p3 = (1.0f - 2.0f * __builtin_amdgcn_rcpf(e2b + 1.0f)) * PI_F;
  const double GAM = 1024.0 / 1023.0;   // table-step rescale (linspace endpoint)
  int h0 = t >> 6, d0 = t & 63, h1 = h0 + 4;
  float c10 = (float)((double)fr[h0] * GAM);
  float s10 = (float)((double)psh[h0] * GAM);
  float c11 = (float)((double)fr[h1] * GAM);
  float s11 = (float)((double)psh[h1] * GAM);
  float A0 = fmaf(p2, c10, s10), Bp0 = p2 * c10;
  float A1 = fmaf(p3, c11, s11), Bp1 = p3 * c11;
  float cA0, sA0, cB0, sB0, cA1, sA1, cB1, sB1;
  __sincosf(A0, &sA0, &cA0);    // |args| < 0.5 rad; abs err ~5e-7 << bf16 round
  __sincosf(Bp0, &sB0, &cB0);
  __sincosf(A1, &sA1, &cA1);
  __sincosf(Bp1, &sB1, &cB1);
  size_t b0 = ((size_t)h0 * 2048 + i) * 128 + d0;
  size_t b1 = ((size_t)h1 * 2048 + i) * 128 + d0;
  Ub[b0] = f2bf(af0 * cA0);  Ub[b0 + 64] = f2bf(af0 * sA0);
  Wb[b0] = f2bf(af0 * cB0);  Wb[b0 + 64] = f2bf(af0 * sB0);
  Ub[b1] = f2bf(af1 * cA1);  Ub[b1 + 64] = f2bf(af1 * sA1);
  Wb[b1] = f2bf(af1 * cB1);  Wb[b1 + 64] = f2bf(af1 * sB1);
}

// ------- single-pass MFMA flash: full k per block, in-kernel normalize -------
// 512 thr = 8 waves: qw = wave&3 (16-q group), kw = wave>>2 (64-k half of the
// 128-k tile). Double-buffered staging; O/den halves combined in LDS at end.
__global__ __launch_bounds__(512, 2) void k_flash5(const unsigned short* __restrict__ Ub,
    const unsigned short* __restrict__ Wb, const unsigned short* __restrict__ vT,
    unsigned short* __restrict__ attb) {
  __shared__ __align__(16) unsigned char s_w[2][128 * 272];  // [k][f 128 bf16 + pad]
  __shared__ __align__(16) unsigned char s_v[2][64 * 272];   // [d][k 128 bf16 + pad]
  __shared__ __align__(16) unsigned char s_p[8][16 * 144];   // per wave [q 16][k 64 + pad]
  const int qt = blockIdx.x, h = blockIdx.y;
  const int q0 = qt * 64;
  const int t = threadIdx.x;
  const int wave = t >> 6, lane = t & 63;
  const int qw = wave & 3, kw = wave >> 2;
  const int m = lane & 15, quad = lane >> 4;
  const int sr = t >> 2, sp = t & 3;      // s_w staging: 128 rows x 4 parts
  const int vr = t >> 3, vp = t & 7;      // s_v staging: 64 rows x 8 parts
  unsigned char* s_pw = s_p[wave];
  // preload U A-frags (q-side, k-invariant)
  short8 afr[4];
  const unsigned short* urow = Ub + ((size_t)h * 2048 + q0 + qw * 16 + m) * 128;
  #pragma unroll
  for (int fs = 0; fs < 4; ++fs)
    afr[fs] = *(const short8*)(urow + fs * 32 + quad * 8);
  short8 ones;
  #pragma unroll
  for (int j = 0; j < 8; ++j) ones[j] = (short)0x3F80;   // bf16 1.0
  f32x4 oacc[4] = {{0,0,0,0},{0,0,0,0},{0,0,0,0},{0,0,0,0}};
  f32x4 dacc = {0, 0, 0, 0};
  const unsigned short* wgbase = Wb + (size_t)h * 2048 * 128 + (size_t)sr * 128;
  const unsigned short* vgbase = vT + ((size_t)h * 64 + vr) * 2048;
  // prologue: stage kt=0 into buffer 0
  #pragma unroll
  for (int it = 0; it < 4; ++it)
    *(short8*)(s_w[0] + sr * 272 + sp * 64 + it * 16) =
      *(const short8*)(wgbase + sp * 32 + it * 8);
  #pragma unroll
  for (int it = 0; it < 2; ++it)
    *(short8*)(s_v[0] + vr * 272 + vp * 32 + it * 16) =
      *(const short8*)(vgbase + vp * 16 + it * 8);
  __syncthreads();
  for (int kt = 0; kt < 16; ++kt) {
    const int cur = kt & 1;
    // issue next tile's global loads (latency overlaps score MFMAs)
    short8 wst[4], vst[2];
    const bool has = (kt < 15);
    if (has) {
      const unsigned short* wg = wgbase + (size_t)(kt + 1) * 128 * 128;
      #pragma unroll
      for (int it = 0; it < 4; ++it)
        wst[it] = *(const short8*)(wg + sp * 32 + it * 8);
      const unsigned short* vg = vgbase + (kt + 1) * 128;
      #pragma unroll
      for (int it = 0; it < 2; ++it)
        vst[it] = *(const short8*)(vg + vp * 16 + it * 8);
    }
    // scores: S[16q x 64k-half] per wave
    f32x4 sc[4] = {{0,0,0,0},{0,0,0,0},{0,0,0,0},{0,0,0,0}};
    #pragma unroll
    for (int ksub = 0; ksub < 4; ++ksub) {
      const int krow = kw * 64 + ksub * 16 + m;
      #pragma unroll
      for (int fs = 0; fs < 4; ++fs) {
        short8 bfr = *(const short8*)(s_w[cur] + krow * 272 + fs * 64 + quad * 16);
        sc[ksub] = MFMA16(afr[fs], bfr, sc[ksub]);
      }
    }
    // p = exp(S/8) -> per-wave LDS region (C-layout write, A-layout re-read)
    #pragma unroll
    for (int ksub = 0; ksub < 4; ++ksub)
      #pragma unroll
      for (int r = 0; r < 4; ++r) {
        float p = __expf(sc[ksub][r] * 0.125f);
        *(unsigned short*)(s_pw + (quad * 4 + r) * 144 + (ksub * 16 + m) * 2) = f2bf(p);
      }
    // commit staged tile to the other buffer
    if (has) {
      #pragma unroll
      for (int it = 0; it < 4; ++it)
        *(short8*)(s_w[cur ^ 1] + sr * 272 + sp * 64 + it * 16) = wst[it];
      #pragma unroll
      for (int it = 0; it < 2; ++it)
        *(short8*)(s_v[cur ^ 1] + vr * 272 + vp * 32 + it * 16) = vst[it];
    }
    __syncthreads();
    // PV + den via MFMA over this wave's 64-k half
    #pragma unroll
    for (int k2 = 0; k2 < 2; ++k2) {
      short8 pf = *(const short8*)(s_pw + m * 144 + k2 * 64 + quad * 16);
      dacc = MFMA16(pf, ones, dacc);
      #pragma unroll
      for (int dt = 0; dt < 4; ++dt) {
        short8 vf = *(const short8*)(s_v[cur] + (dt * 16 + m) * 272 +
                                     kw * 128 + k2 * 64 + quad * 16);
        oacc[dt] = MFMA16(pf, vf, oacc[dt]);
      }
    }
    __syncthreads();
  }
  // combine k-halves in LDS (reuse s_w[0]): kw=1 writes, kw=0 reduces+stores
  float* s_ored = (float*)(s_w[0]);              // [qw][16 q][64 d]
  float* s_dred = (float*)(s_w[0] + 16384);      // [qw][16 q]
  if (kw == 1) {
    #pragma unroll
    for (int dt = 0; dt < 4; ++dt)
      #pragma unroll
      for (int r = 0; r < 4; ++r)
        s_ored[qw * 1024 + (quad * 4 + r) * 64 + dt * 16 + m] = oacc[dt][r];
    if (m == 0) {
      #pragma unroll
      for (int r = 0; r < 4; ++r)
        s_dred[qw * 16 + quad * 4 + r] = dacc[r];
    }
  }
  __syncthreads();
  if (kw == 0) {
    float invd[4];
    #pragma unroll
    for (int r = 0; r < 4; ++r)
      invd[r] = 1.0f / (dacc[r] + s_dred[qw * 16 + quad * 4 + r]);
    #pragma unroll
    for (int dt = 0; dt < 4; ++dt)
      #pragma unroll
      for (int r = 0; r < 4; ++r) {
        float o = oacc[dt][r] + s_ored[qw * 1024 + (quad * 4 + r) * 64 + dt * 16 + m];
        attb[(size_t)(q0 + qw * 16 + quad * 4 + r) * 512 + h * 64 + dt * 16 + m] =
            f2bf(o * invd[r]);
      }
  }
}

extern "C" void kernel_launch(void* const* d_in, const int* in_sizes, int n_in,
                              void* d_out, int out_size, void* d_ws, size_t ws_size,
                              hipStream_t stream) {
  (void)in_sizes; (void)n_in; (void)out_size; (void)ws_size;
  const float* x   = (const float*)d_in[0];
  const float* Wq  = (const float*)d_in[1];
  const float* bq  = (const float*)d_in[2];
  const float* lnw = (const float*)d_in[3];
  const float* lnb = (const float*)d_in[4];
  const float* fr  = (const float*)d_in[5];
  const float* ps  = (const float*)d_in[6];
  const float* Wo  = (const float*)d_in[7];
  const float* bo  = (const float*)d_in[8];
  // d_in[9] = cos_table: unused (smooth-cos factorization)
  char* ws = (char*)d_ws;
  float*          qs   = (float*)(ws + B_QS);
  unsigned short* attb = (unsigned short*)(ws + B_ATTB);   // reuses qs region
  unsigned short* Ub   = (unsigned short*)(ws + B_UB);
  unsigned short* Wb   = (unsigned short*)(ws + B_WB);
  unsigned short* xb   = (unsigned short*)(ws + B_XB);
  unsigned short* vT   = (unsigned short*)(ws + B_VT);
  unsigned short* WqT  = (unsigned short*)(ws + B_WQT);
  unsigned short* WoT  = (unsigned short*)(ws + B_WOT);
  float* out = (float*)d_out;

  k_prep<<<448, 256, 0, stream>>>(x, Wq, Wo, xb, vT, WqT, WoT);
  k_gemm<<<dim3(32, 16), 256, 0, stream>>>(xb, WqT, bq, qs, 1024);
  k_ln_act<<<2048, 256, 0, stream>>>(qs, lnw, lnb, fr, ps, Ub, Wb);
  k_flash5<<<dim3(32, 8), 512, 0, stream>>>(Ub, Wb, vT, attb);
  k_gemm<<<dim3(32, 8), 256, 0, stream>>>(attb, WoT, bo, out, 512);
}

// Round 7
// 150.628 us; speedup vs baseline: 4.9666x; 1.0355x over previous
//
#include <hip/hip_runtime.h>
#include <cstdint>
#include <cstddef>

// B=1, L=2048, DIM=512, H=8, D=64, STEPS=1024.  R7: 4-kernel all-MFMA pipeline.
// R7 changes vs R6:
//  - k_qs_ln: qs-GEMM + LayerNorm + sigmoid/L2norm + tanh + cos/sin feature
//    build fused into ONE kernel (block = 16 full rows; row stats in-block).
//    qs 8MB f32 buffer and the ln_act dispatch eliminated.  B-operand read
//    directly from global in frag-packed order (WqTp), no LDS staging.
//  - k_prep: writes WqTp (frag-packed Wq^T), vT, WoT; xb eliminated.
//  - k_flash5: single barrier per k-tile (commit after PV; the per-wave P
//    LDS roundtrip needs no barrier).
//
//  pipeline: k_prep -> k_qs_ln -> k_flash5 -> k_gemm(out)

typedef __attribute__((ext_vector_type(8))) short short8;
typedef __attribute__((ext_vector_type(4))) float f32x4;

#define MFMA16(a, b, c) __builtin_amdgcn_mfma_f32_16x16x32_bf16((a), (b), (c), 0, 0, 0)

static constexpr size_t B_ATTB = 0;                        // bf16 [2048][512] = 2 MB
static constexpr size_t B_UB   = (size_t)2 * 1024 * 1024;  // bf16 [8][2048][128] = 4 MB
static constexpr size_t B_WB   = B_UB + (size_t)4 * 1024 * 1024;
static constexpr size_t B_VT   = B_WB + (size_t)4 * 1024 * 1024;   // bf16 [8][64][2048]
static constexpr size_t B_WQT  = B_VT + (size_t)2 * 1024 * 1024;   // frag-packed, 1 MB
static constexpr size_t B_WOT  = B_WQT + (size_t)1 * 1024 * 1024;  // bf16 [512][512]

__device__ __forceinline__ unsigned short f2bf(float f) {
  unsigned u = __float_as_uint(f);
  return (unsigned short)((u + 0x7FFFu + ((u >> 16) & 1u)) >> 16);
}

// ---------------- prep: x -> vT;  Wq -> WqTp (frag-packed);  Wo -> WoT ----------
__global__ __launch_bounds__(256) void k_prep(const float* __restrict__ x,
    const float* __restrict__ Wq, const float* __restrict__ Wo,
    unsigned short* __restrict__ vT, unsigned short* __restrict__ WqTp,
    unsigned short* __restrict__ WoT) {
  __shared__ float tl[64 * 65];
  const int t = threadIdx.x, b = blockIdx.x;
  if (b < 256) {
    const int i0 = (b >> 3) * 64, h = b & 7;
    #pragma unroll
    for (int it = 0; it < 16; ++it) {
      int n = t + 256 * it;
      int r = n >> 6, c = n & 63;
      tl[r * 65 + c] = x[(size_t)(i0 + r) * 512 + h * 64 + c];
    }
    __syncthreads();
    #pragma unroll
    for (int it = 0; it < 16; ++it) {
      int n = t + 256 * it;
      int d = n >> 6, ii = n & 63;
      vT[(size_t)(h * 64 + d) * 2048 + i0 + ii] = f2bf(tl[ii * 65 + d]);
    }
  } else if (b < 384) {
    const int bb = b - 256;
    const int k0 = (bb >> 4) * 64, n0 = (bb & 15) * 64;
    #pragma unroll
    for (int it = 0; it < 16; ++it) {
      int n = t + 256 * it;
      int r = n >> 6, c = n & 63;
      tl[r * 65 + c] = Wq[(size_t)(k0 + r) * 1024 + n0 + c];
    }
    __syncthreads();
    #pragma unroll
    for (int it = 0; it < 16; ++it) {
      int n = t + 256 * it;
      int rr = n >> 6, cc = n & 63;       // rr = n-local, cc = k-local
      int nn = n0 + rr, kk = k0 + cc;
      int nt = nn >> 4, mm = nn & 15;
      int kc32 = kk >> 5, qd = (kk >> 3) & 3, j = kk & 7;
      // frag-packed: granule ((nt*16 + kc32)*64 + qd*16 + mm), elem j
      WqTp[(((size_t)nt * 16 + kc32) * 64 + qd * 16 + mm) * 8 + j] =
          f2bf(tl[cc * 65 + rr]);
    }
  } else {
    const int bb = b - 384;
    const int k0 = (bb >> 3) * 64, n0 = (bb & 7) * 64;
    #pragma unroll
    for (int it = 0; it < 16; ++it) {
      int n = t + 256 * it;
      int r = n >> 6, c = n & 63;
      tl[r * 65 + c] = Wo[(size_t)(k0 + r) * 512 + n0 + c];
    }
    __syncthreads();
    #pragma unroll
    for (int it = 0; it < 16; ++it) {
      int n = t + 256 * it;
      int rr = n >> 6, cc = n & 63;
      WoT[(size_t)(n0 + rr) * 512 + k0 + cc] = f2bf(tl[cc * 65 + rr]);
    }
  }
}

// -------- fused qs-GEMM + LN + activations + cos/sin features ----------------
// Block = 16 rows x all 1024 cols.  512 thr = 8 waves; wave w owns cols
// [128w, 128w+128).  Waves 0-3: amp half; waves 4-7: phase half.
__global__ __launch_bounds__(512) void k_qs_ln(const float* __restrict__ x,
    const unsigned short* __restrict__ WqTp, const float* __restrict__ bq,
    const float* __restrict__ lnw, const float* __restrict__ lnb,
    const float* __restrict__ fr, const float* __restrict__ psh,
    unsigned short* __restrict__ Ub, unsigned short* __restrict__ Wb) {
  __shared__ __align__(16) unsigned short s_a[16 * 520];  // A rows, stride 520 bf16
  __shared__ float s_amp[16 * 516];                       // normalized amp [row][col]
  __shared__ float red[8 * 16 * 2];                       // rowstats [wave][row][{s,s2}]
  __shared__ float red2[4 * 16];                          // amp-norm [ampwave][row]
  const int r0 = blockIdx.x * 16, t = threadIdx.x;
  const int w = t >> 6, lane = t & 63, m = lane & 15, quad = lane >> 4;
  // stage A: 16 rows of x, cast bf16 (32 thr/row, 16 cols each)
  {
    const int row = t >> 5, cs = (t & 31) * 16;
    const float4* xr = (const float4*)(x + (size_t)(r0 + row) * 512 + cs);
    unsigned short tmp[16];
    #pragma unroll
    for (int q4 = 0; q4 < 4; ++q4) {
      float4 v = xr[q4];
      tmp[q4 * 4 + 0] = f2bf(v.x); tmp[q4 * 4 + 1] = f2bf(v.y);
      tmp[q4 * 4 + 2] = f2bf(v.z); tmp[q4 * 4 + 3] = f2bf(v.w);
    }
    *(short8*)(s_a + row * 520 + cs)     = *(short8*)(tmp);
    *(short8*)(s_a + row * 520 + cs + 8) = *(short8*)(tmp + 8);
  }
  __syncthreads();
  // GEMM: acc[nt] covers col = 128w + nt*16 + m, row = quad*4 + r
  f32x4 acc[8] = {{0,0,0,0},{0,0,0,0},{0,0,0,0},{0,0,0,0},
                  {0,0,0,0},{0,0,0,0},{0,0,0,0},{0,0,0,0}};
  for (int kc32 = 0; kc32 < 16; ++kc32) {
    short8 af = *(const short8*)(s_a + m * 520 + kc32 * 32 + quad * 8);
    const unsigned short* bp =
        WqTp + (((size_t)(w * 8) * 16 + kc32) * 64 + lane) * 8;
    #pragma unroll
    for (int nt = 0; nt < 8; ++nt) {
      short8 bf = *(const short8*)(bp + (size_t)nt * 8192);
      acc[nt] = MFMA16(af, bf, acc[nt]);
    }
  }
  // + bias, then row stats over all 1024 cols
  #pragma unroll
  for (int nt = 0; nt < 8; ++nt) {
    float bv = bq[w * 128 + nt * 16 + m];
    #pragma unroll
    for (int r = 0; r < 4; ++r) acc[nt][r] += bv;
  }
  float s1[4] = {0, 0, 0, 0}, s2[4] = {0, 0, 0, 0};
  #pragma unroll
  for (int r = 0; r < 4; ++r)
    #pragma unroll
    for (int nt = 0; nt < 8; ++nt) {
      float v = acc[nt][r];
      s1[r] += v; s2[r] += v * v;
    }
  #pragma unroll
  for (int off = 1; off < 16; off <<= 1)
    #pragma unroll
    for (int r = 0; r < 4; ++r) {
      s1[r] += __shfl_xor(s1[r], off, 64);
      s2[r] += __shfl_xor(s2[r], off, 64);
    }
  if (m == 0)
    #pragma unroll
    for (int r = 0; r < 4; ++r) {
      red[(w * 16 + quad * 4 + r) * 2]     = s1[r];
      red[(w * 16 + quad * 4 + r) * 2 + 1] = s2[r];
    }
  __syncthreads();
  float mu[4], rstd[4];
  #pragma unroll
  for (int r = 0; r < 4; ++r) {
    int row = quad * 4 + r;
    float S = 0, S2 = 0;
    #pragma unroll
    for (int wp = 0; wp < 8; ++wp) {
      S  += red[(wp * 16 + row) * 2];
      S2 += red[(wp * 16 + row) * 2 + 1];
    }
    mu[r] = S * (1.0f / 1024.0f);
    float var = S2 * (1.0f / 1024.0f) - mu[r] * mu[r];
    rstd[r] = 1.0f / sqrtf(var + 1e-5f);
  }
  float y[8][4];
  #pragma unroll
  for (int nt = 0; nt < 8; ++nt) {
    int c = w * 128 + nt * 16 + m;
    float gw = lnw[c], gb = lnb[c];
    #pragma unroll
    for (int r = 0; r < 4; ++r)
      y[nt][r] = (acc[nt][r] - mu[r]) * rstd[r] * gw + gb;
  }
  const float PI_F = 3.14159265358979323846f;
  if (w < 4) {
    // amp half: sigmoid, row L2-norm over 512 amp cols, write s_amp
    float a[8][4];
    float na[4] = {0, 0, 0, 0};
    #pragma unroll
    for (int nt = 0; nt < 8; ++nt)
      #pragma unroll
      for (int r = 0; r < 4; ++r) {
        float v = __builtin_amdgcn_rcpf(1.0f + __expf(-y[nt][r]));
        a[nt][r] = v;
        na[r] += v * v;
      }
    #pragma unroll
    for (int off = 1; off < 16; off <<= 1)
      #pragma unroll
      for (int r = 0; r < 4; ++r) na[r] += __shfl_xor(na[r], off, 64);
    if (m == 0)
      #pragma unroll
      for (int r = 0; r < 4; ++r) red2[w * 16 + quad * 4 + r] = na[r];
    __syncthreads();   // #3: red2 ready
    float inv[4];
    #pragma unroll
    for (int r = 0; r < 4; ++r) {
      int row = quad * 4 + r;
      float N = red2[row] + red2[16 + row] + red2[32 + row] + red2[48 + row];
      inv[r] = 1.0f / (sqrtf(N) + 1e-8f);
    }
    #pragma unroll
    for (int nt = 0; nt < 8; ++nt)
      #pragma unroll
      for (int r = 0; r < 4; ++r)
        s_amp[(quad * 4 + r) * 516 + w * 128 + nt * 16 + m] = a[nt][r] * inv[r];
    __syncthreads();   // #4: s_amp ready (amp waves done after this)
  } else {
    // phase half: fast tanh -> p; features after s_amp is ready
    float p[8][4];
    #pragma unroll
    for (int nt = 0; nt < 8; ++nt)
      #pragma unroll
      for (int r = 0; r < 4; ++r) {
        float e2 = __expf(2.0f * y[nt][r]);
        p[nt][r] = (1.0f - 2.0f * __builtin_amdgcn_rcpf(e2 + 1.0f)) * PI_F;
      }
    __syncthreads();   // #3 (match amp waves)
    __syncthreads();   // #4: s_amp ready
    const double GAM = 1024.0 / 1023.0;   // table-step rescale (linspace endpoint)
    const int hbase = (w - 4) * 2;
    float c1[2], s1g[2];
    #pragma unroll
    for (int hh = 0; hh < 2; ++hh) {
      c1[hh]  = (float)((double)fr[hbase + hh] * GAM);
      s1g[hh] = (float)((double)psh[hbase + hh] * GAM);
    }
    #pragma unroll
    for (int nt = 0; nt < 8; ++nt) {
      const int hh = nt >> 2;
      const int pc = (w - 4) * 128 + nt * 16 + m;   // phase col in [0,512)
      const int d = pc & 63;
      #pragma unroll
      for (int r = 0; r < 4; ++r) {
        const int i = r0 + quad * 4 + r;
        float af = s_amp[(quad * 4 + r) * 516 + pc];
        float A = fmaf(p[nt][r], c1[hh], s1g[hh]);
        float Bp = p[nt][r] * c1[hh];
        float cA, sA, cB, sB;
        __sincosf(A, &sA, &cA);
        __sincosf(Bp, &sB, &cB);
        size_t base = ((size_t)(hbase + hh) * 2048 + i) * 128 + d;
        Ub[base]      = f2bf(af * cA);
        Ub[base + 64] = f2bf(af * sA);
        Wb[base]      = f2bf(af * cB);
        Wb[base + 64] = f2bf(af * sB);
      }
    }
  }
}

// ------- single-pass MFMA flash: full k per block, 1 barrier per k-tile -------
__global__ __launch_bounds__(512, 2) void k_flash5(const unsigned short* __restrict__ Ub,
    const unsigned short* __restrict__ Wb, const unsigned short* __restrict__ vT,
    unsigned short* __restrict__ attb) {
  __shared__ __align__(16) unsigned char s_w[2][128 * 272];  // [k][f 128 bf16 + pad]
  __shared__ __align__(16) unsigned char s_v[2][64 * 272];   // [d][k 128 bf16 + pad]
  __shared__ __align__(16) unsigned char s_p[8][16 * 144];   // per wave [q 16][k 64 + pad]
  const int qt = blockIdx.x, h = blockIdx.y;
  const int q0 = qt * 64;
  const int t = threadIdx.x;
  const int wave = t >> 6, lane = t & 63;
  const int qw = wave & 3, kw = wave >> 2;
  const int m = lane & 15, quad = lane >> 4;
  const int sr = t >> 2, sp = t & 3;      // s_w staging: 128 rows x 4 parts
  const int vr = t >> 3, vp = t & 7;      // s_v staging: 64 rows x 8 parts
  unsigned char* s_pw = s_p[wave];
  short8 afr[4];
  const unsigned short* urow = Ub + ((size_t)h * 2048 + q0 + qw * 16 + m) * 128;
  #pragma unroll
  for (int fs = 0; fs < 4; ++fs)
    afr[fs] = *(const short8*)(urow + fs * 32 + quad * 8);
  short8 ones;
  #pragma unroll
  for (int j = 0; j < 8; ++j) ones[j] = (short)0x3F80;   // bf16 1.0
  f32x4 oacc[4] = {{0,0,0,0},{0,0,0,0},{0,0,0,0},{0,0,0,0}};
  f32x4 dacc = {0, 0, 0, 0};
  const unsigned short* wgbase = Wb + (size_t)h * 2048 * 128 + (size_t)sr * 128;
  const unsigned short* vgbase = vT + ((size_t)h * 64 + vr) * 2048;
  #pragma unroll
  for (int it = 0; it < 4; ++it)
    *(short8*)(s_w[0] + sr * 272 + sp * 64 + it * 16) =
      *(const short8*)(wgbase + sp * 32 + it * 8);
  #pragma unroll
  for (int it = 0; it < 2; ++it)
    *(short8*)(s_v[0] + vr * 272 + vp * 32 + it * 16) =
      *(const short8*)(vgbase + vp * 16 + it * 8);
  __syncthreads();
  for (int kt = 0; kt < 16; ++kt) {
    const int cur = kt & 1;
    short8 wst[4], vst[2];
    const bool has = (kt < 15);
    if (has) {
      const unsigned short* wg = wgbase + (size_t)(kt + 1) * 128 * 128;
      #pragma unroll
      for (int it = 0; it < 4; ++it)
        wst[it] = *(const short8*)(wg + sp * 32 + it * 8);
      const unsigned short* vg = vgbase + (kt + 1) * 128;
      #pragma unroll
      for (int it = 0; it < 2; ++it)
        vst[it] = *(const short8*)(vg + vp * 16 + it * 8);
    }
    // scores: S[16q x 64k-half] per wave
    f32x4 sc[4] = {{0,0,0,0},{0,0,0,0},{0,0,0,0},{0,0,0,0}};
    #pragma unroll
    for (int ksub = 0; ksub < 4; ++ksub) {
      const int krow = kw * 64 + ksub * 16 + m;
      #pragma unroll
      for (int fs = 0; fs < 4; ++fs) {
        short8 bfr = *(const short8*)(s_w[cur] + krow * 272 + fs * 64 + quad * 16);
        sc[ksub] = MFMA16(afr[fs], bfr, sc[ksub]);
      }
    }
    // p = exp(S/8) -> own-wave LDS region (no barrier needed: same-wave RAW)
    #pragma unroll
    for (int ksub = 0; ksub < 4; ++ksub)
      #pragma unroll
      for (int r = 0; r < 4; ++r) {
        float p = __expf(sc[ksub][r] * 0.125f);
        *(unsigned short*)(s_pw + (quad * 4 + r) * 144 + (ksub * 16 + m) * 2) = f2bf(p);
      }
    // PV + den via MFMA over this wave's 64-k half
    #pragma unroll
    for (int k2 = 0; k2 < 2; ++k2) {
      short8 pf = *(const short8*)(s_pw + m * 144 + k2 * 64 + quad * 16);
      dacc = MFMA16(pf, ones, dacc);
      #pragma unroll
      for (int dt = 0; dt < 4; ++dt) {
        short8 vf = *(const short8*)(s_v[cur] + (dt * 16 + m) * 272 +
                                     kw * 128 + k2 * 64 + quad * 16);
        oacc[dt] = MFMA16(pf, vf, oacc[dt]);
      }
    }
    // commit staged tile AFTER PV -> single barrier per kt
    if (has) {
      #pragma unroll
      for (int it = 0; it < 4; ++it)
        *(short8*)(s_w[cur ^ 1] + sr * 272 + sp * 64 + it * 16) = wst[it];
      #pragma unroll
      for (int it = 0; it < 2; ++it)
        *(short8*)(s_v[cur ^ 1] + vr * 272 + vp * 32 + it * 16) = vst[it];
    }
    __syncthreads();
  }
  // combine k-halves in LDS (reuse s_w[0]): kw=1 writes, kw=0 reduces+stores
  float* s_ored = (float*)(s_w[0]);              // [qw][16 q][64 d]
  float* s_dred = (float*)(s_w[0] + 16384);      // [qw][16 q]
  if (kw == 1) {
    #pragma unroll
    for (int dt = 0; dt < 4; ++dt)
      #pragma unroll
      for (int r = 0; r < 4; ++r)
        s_ored[qw * 1024 + (quad * 4 + r) * 64 + dt * 16 + m] = oacc[dt][r];
    if (m == 0) {
      #pragma unroll
      for (int r = 0; r < 4; ++r)
        s_dred[qw * 16 + quad * 4 + r] = dacc[r];
    }
  }
  __syncthreads();
  if (kw == 0) {
    float invd[4];
    #pragma unroll
    for (int r = 0; r < 4; ++r)
      invd[r] = 1.0f / (dacc[r] + s_dred[qw * 16 + quad * 4 + r]);
    #pragma unroll
    for (int dt = 0; dt < 4; ++dt)
      #pragma unroll
      for (int r = 0; r < 4; ++r) {
        float o = oacc[dt][r] + s_ored[qw * 1024 + (quad * 4 + r) * 64 + dt * 16 + m];
        attb[(size_t)(q0 + qw * 16 + quad * 4 + r) * 512 + h * 64 + dt * 16 + m] =
            f2bf(o * invd[r]);
      }
  }
}

// ------- out GEMM: out f32 = attb @ WoT^T + bo ----------------
__global__ __launch_bounds__(256) void k_gemm(const unsigned short* __restrict__ A,
    const unsigned short* __restrict__ Bt, const float* __restrict__ bias,
    float* __restrict__ C, int N) {
  __shared__ __align__(16) unsigned char sm[2 * 64 * 136];
  unsigned char* s_a = sm;
  unsigned char* s_b = sm + 64 * 136;
  const int m0 = blockIdx.x * 64, n0 = blockIdx.y * 64;
  const int t = threadIdx.x;
  const int wave = t >> 6, lane = t & 63;
  const int m = lane & 15, quad = lane >> 4;
  const int sr = t >> 2, spart = t & 3;
  f32x4 acc[4] = {{0,0,0,0},{0,0,0,0},{0,0,0,0},{0,0,0,0}};
  for (int kc = 0; kc < 512; kc += 64) {
    #pragma unroll
    for (int it = 0; it < 2; ++it) {
      *(short8*)(s_a + sr * 136 + spart * 32 + it * 16) =
        *(const short8*)(A + (size_t)(m0 + sr) * 512 + kc + spart * 16 + it * 8);
      *(short8*)(s_b + sr * 136 + spart * 32 + it * 16) =
        *(const short8*)(Bt + (size_t)(n0 + sr) * 512 + kc + spart * 16 + it * 8);
    }
    __syncthreads();
    #pragma unroll
    for (int k2 = 0; k2 < 2; ++k2) {
      short8 af = *(const short8*)(s_a + (wave * 16 + m) * 136 + k2 * 64 + quad * 16);
      #pragma unroll
      for (int nt = 0; nt < 4; ++nt) {
        short8 bf = *(const short8*)(s_b + (nt * 16 + m) * 136 + k2 * 64 + quad * 16);
        acc[nt] = MFMA16(af, bf, acc[nt]);
      }
    }
    __syncthreads();
  }
  #pragma unroll
  for (int nt = 0; nt < 4; ++nt) {
    int col = n0 + nt * 16 + m;
    float bv = bias[col];
    #pragma unroll
    for (int r = 0; r < 4; ++r) {
      int row = m0 + wave * 16 + quad * 4 + r;
      C[(size_t)row * N + col] = acc[nt][r] + bv;
    }
  }
}

extern "C" void kernel_launch(void* const* d_in, const int* in_sizes, int n_in,
                              void* d_out, int out_size, void* d_ws, size_t ws_size,
                              hipStream_t stream) {
  (void)in_sizes; (void)n_in; (void)out_size; (void)ws_size;
  const float* x   = (const float*)d_in[0];
  const float* Wq  = (const float*)d_in[1];
  const float* bq  = (const float*)d_in[2];
  const float* lnw = (const float*)d_in[3];
  const float* lnb = (const float*)d_in[4];
  const float* fr  = (const float*)d_in[5];
  const float* ps  = (const float*)d_in[6];
  const float* Wo  = (const float*)d_in[7];
  const float* bo  = (const float*)d_in[8];
  // d_in[9] = cos_table: unused (smooth-cos factorization)
  char* ws = (char*)d_ws;
  unsigned short* attb = (unsigned short*)(ws + B_ATTB);
  unsigned short* Ub   = (unsigned short*)(ws + B_UB);
  unsigned short* Wb   = (unsigned short*)(ws + B_WB);
  unsigned short* vT   = (unsigned short*)(ws + B_VT);
  unsigned short* WqTp = (unsigned short*)(ws + B_WQT);
  unsigned short* WoT  = (unsigned short*)(ws + B_WOT);
  float* out = (float*)d_out;

  k_prep<<<448, 256, 0, stream>>>(x, Wq, Wo, vT, WqTp, WoT);
  k_qs_ln<<<128, 512, 0, stream>>>(x, WqTp, bq, lnw, lnb, fr, ps, Ub, Wb);
  k_flash5<<<dim3(32, 8), 512, 0, stream>>>(Ub, Wb, vT, attb);
  k_gemm<<<dim3(32, 8), 256, 0, stream>>>(attb, WoT, bo, out, 512);
}

// Round 8
// 146.971 us; speedup vs baseline: 5.0902x; 1.0249x over previous
//
#include <hip/hip_runtime.h>
#include <cstdint>
#include <cstddef>

// B=1, L=2048, DIM=512, H=8, D=64, STEPS=1024.  R8: 4-kernel all-MFMA pipeline.
// R8 change: k_flash6 wave->work remap kills LDS read redundancy:
//   scores: wave owns a 16-k strip (4 B-frag reads/kt, was 16; U A-frags for
//   all 4 q-groups preloaded in regs), PV: wave owns (16q x 32d) with vf
//   preloaded to regs pre-barrier; every wave computes its own den (redundant
//   MFMA instead of LDS exchange); k-half combine epilogue eliminated.
//   26 -> 16 b128 reads per wave per k-tile; 1 barrier/kt; s_p double-buffered.
// Timing model note: measured dur includes ~86us of harness ws-repoison fills
// (268MB @ ~6.3TB/s); addressable kernel+gap pool is ~64us at R7.
//
//  pipeline: k_prep -> k_qs_ln -> k_flash6 -> k_gemm(out)

typedef __attribute__((ext_vector_type(8))) short short8;
typedef __attribute__((ext_vector_type(4))) float f32x4;

#define MFMA16(a, b, c) __builtin_amdgcn_mfma_f32_16x16x32_bf16((a), (b), (c), 0, 0, 0)

static constexpr size_t B_ATTB = 0;                        // bf16 [2048][512] = 2 MB
static constexpr size_t B_UB   = (size_t)2 * 1024 * 1024;  // bf16 [8][2048][128] = 4 MB
static constexpr size_t B_WB   = B_UB + (size_t)4 * 1024 * 1024;
static constexpr size_t B_VT   = B_WB + (size_t)4 * 1024 * 1024;   // bf16 [8][64][2048]
static constexpr size_t B_WQT  = B_VT + (size_t)2 * 1024 * 1024;   // frag-packed, 1 MB
static constexpr size_t B_WOT  = B_WQT + (size_t)1 * 1024 * 1024;  // bf16 [512][512]

__device__ __forceinline__ unsigned short f2bf(float f) {
  unsigned u = __float_as_uint(f);
  return (unsigned short)((u + 0x7FFFu + ((u >> 16) & 1u)) >> 16);
}

// ---------------- prep: x -> vT;  Wq -> WqTp (frag-packed);  Wo -> WoT ----------
__global__ __launch_bounds__(256) void k_prep(const float* __restrict__ x,
    const float* __restrict__ Wq, const float* __restrict__ Wo,
    unsigned short* __restrict__ vT, unsigned short* __restrict__ WqTp,
    unsigned short* __restrict__ WoT) {
  __shared__ float tl[64 * 65];
  const int t = threadIdx.x, b = blockIdx.x;
  if (b < 256) {
    const int i0 = (b >> 3) * 64, h = b & 7;
    #pragma unroll
    for (int it = 0; it < 16; ++it) {
      int n = t + 256 * it;
      int r = n >> 6, c = n & 63;
      tl[r * 65 + c] = x[(size_t)(i0 + r) * 512 + h * 64 + c];
    }
    __syncthreads();
    #pragma unroll
    for (int it = 0; it < 16; ++it) {
      int n = t + 256 * it;
      int d = n >> 6, ii = n & 63;
      vT[(size_t)(h * 64 + d) * 2048 + i0 + ii] = f2bf(tl[ii * 65 + d]);
    }
  } else if (b < 384) {
    const int bb = b - 256;
    const int k0 = (bb >> 4) * 64, n0 = (bb & 15) * 64;
    #pragma unroll
    for (int it = 0; it < 16; ++it) {
      int n = t + 256 * it;
      int r = n >> 6, c = n & 63;
      tl[r * 65 + c] = Wq[(size_t)(k0 + r) * 1024 + n0 + c];
    }
    __syncthreads();
    #pragma unroll
    for (int it = 0; it < 16; ++it) {
      int n = t + 256 * it;
      int rr = n >> 6, cc = n & 63;       // rr = n-local, cc = k-local
      int nn = n0 + rr, kk = k0 + cc;
      int nt = nn >> 4, mm = nn & 15;
      int kc32 = kk >> 5, qd = (kk >> 3) & 3, j = kk & 7;
      WqTp[(((size_t)nt * 16 + kc32) * 64 + qd * 16 + mm) * 8 + j] =
          f2bf(tl[cc * 65 + rr]);
    }
  } else {
    const int bb = b - 384;
    const int k0 = (bb >> 3) * 64, n0 = (bb & 7) * 64;
    #pragma unroll
    for (int it = 0; it < 16; ++it) {
      int n = t + 256 * it;
      int r = n >> 6, c = n & 63;
      tl[r * 65 + c] = Wo[(size_t)(k0 + r) * 512 + n0 + c];
    }
    __syncthreads();
    #pragma unroll
    for (int it = 0; it < 16; ++it) {
      int n = t + 256 * it;
      int rr = n >> 6, cc = n & 63;
      WoT[(size_t)(n0 + rr) * 512 + k0 + cc] = f2bf(tl[cc * 65 + rr]);
    }
  }
}

// -------- fused qs-GEMM + LN + activations + cos/sin features ----------------
__global__ __launch_bounds__(512) void k_qs_ln(const float* __restrict__ x,
    const unsigned short* __restrict__ WqTp, const float* __restrict__ bq,
    const float* __restrict__ lnw, const float* __restrict__ lnb,
    const float* __restrict__ fr, const float* __restrict__ psh,
    unsigned short* __restrict__ Ub, unsigned short* __restrict__ Wb) {
  __shared__ __align__(16) unsigned short s_a[16 * 520];  // A rows, stride 520 bf16
  __shared__ float s_amp[16 * 516];                       // normalized amp [row][col]
  __shared__ float red[8 * 16 * 2];                       // rowstats [wave][row][{s,s2}]
  __shared__ float red2[4 * 16];                          // amp-norm [ampwave][row]
  const int r0 = blockIdx.x * 16, t = threadIdx.x;
  const int w = t >> 6, lane = t & 63, m = lane & 15, quad = lane >> 4;
  {
    const int row = t >> 5, cs = (t & 31) * 16;
    const float4* xr = (const float4*)(x + (size_t)(r0 + row) * 512 + cs);
    unsigned short tmp[16];
    #pragma unroll
    for (int q4 = 0; q4 < 4; ++q4) {
      float4 v = xr[q4];
      tmp[q4 * 4 + 0] = f2bf(v.x); tmp[q4 * 4 + 1] = f2bf(v.y);
      tmp[q4 * 4 + 2] = f2bf(v.z); tmp[q4 * 4 + 3] = f2bf(v.w);
    }
    *(short8*)(s_a + row * 520 + cs)     = *(short8*)(tmp);
    *(short8*)(s_a + row * 520 + cs + 8) = *(short8*)(tmp + 8);
  }
  __syncthreads();
  f32x4 acc[8] = {{0,0,0,0},{0,0,0,0},{0,0,0,0},{0,0,0,0},
                  {0,0,0,0},{0,0,0,0},{0,0,0,0},{0,0,0,0}};
  for (int kc32 = 0; kc32 < 16; ++kc32) {
    short8 af = *(const short8*)(s_a + m * 520 + kc32 * 32 + quad * 8);
    const unsigned short* bp =
        WqTp + (((size_t)(w * 8) * 16 + kc32) * 64 + lane) * 8;
    #pragma unroll
    for (int nt = 0; nt < 8; ++nt) {
      short8 bf = *(const short8*)(bp + (size_t)nt * 8192);
      acc[nt] = MFMA16(af, bf, acc[nt]);
    }
  }
  #pragma unroll
  for (int nt = 0; nt < 8; ++nt) {
    float bv = bq[w * 128 + nt * 16 + m];
    #pragma unroll
    for (int r = 0; r < 4; ++r) acc[nt][r] += bv;
  }
  float s1[4] = {0, 0, 0, 0}, s2[4] = {0, 0, 0, 0};
  #pragma unroll
  for (int r = 0; r < 4; ++r)
    #pragma unroll
    for (int nt = 0; nt < 8; ++nt) {
      float v = acc[nt][r];
      s1[r] += v; s2[r] += v * v;
    }
  #pragma unroll
  for (int off = 1; off < 16; off <<= 1)
    #pragma unroll
    for (int r = 0; r < 4; ++r) {
      s1[r] += __shfl_xor(s1[r], off, 64);
      s2[r] += __shfl_xor(s2[r], off, 64);
    }
  if (m == 0)
    #pragma unroll
    for (int r = 0; r < 4; ++r) {
      red[(w * 16 + quad * 4 + r) * 2]     = s1[r];
      red[(w * 16 + quad * 4 + r) * 2 + 1] = s2[r];
    }
  __syncthreads();
  float mu[4], rstd[4];
  #pragma unroll
  for (int r = 0; r < 4; ++r) {
    int row = quad * 4 + r;
    float S = 0, S2 = 0;
    #pragma unroll
    for (int wp = 0; wp < 8; ++wp) {
      S  += red[(wp * 16 + row) * 2];
      S2 += red[(wp * 16 + row) * 2 + 1];
    }
    mu[r] = S * (1.0f / 1024.0f);
    float var = S2 * (1.0f / 1024.0f) - mu[r] * mu[r];
    rstd[r] = 1.0f / sqrtf(var + 1e-5f);
  }
  float y[8][4];
  #pragma unroll
  for (int nt = 0; nt < 8; ++nt) {
    int c = w * 128 + nt * 16 + m;
    float gw = lnw[c], gb = lnb[c];
    #pragma unroll
    for (int r = 0; r < 4; ++r)
      y[nt][r] = (acc[nt][r] - mu[r]) * rstd[r] * gw + gb;
  }
  const float PI_F = 3.14159265358979323846f;
  if (w < 4) {
    float a[8][4];
    float na[4] = {0, 0, 0, 0};
    #pragma unroll
    for (int nt = 0; nt < 8; ++nt)
      #pragma unroll
      for (int r = 0; r < 4; ++r) {
        float v = __builtin_amdgcn_rcpf(1.0f + __expf(-y[nt][r]));
        a[nt][r] = v;
        na[r] += v * v;
      }
    #pragma unroll
    for (int off = 1; off < 16; off <<= 1)
      #pragma unroll
      for (int r = 0; r < 4; ++r) na[r] += __shfl_xor(na[r], off, 64);
    if (m == 0)
      #pragma unroll
      for (int r = 0; r < 4; ++r) red2[w * 16 + quad * 4 + r] = na[r];
    __syncthreads();   // #3: red2 ready
    float inv[4];
    #pragma unroll
    for (int r = 0; r < 4; ++r) {
      int row = quad * 4 + r;
      float N = red2[row] + red2[16 + row] + red2[32 + row] + red2[48 + row];
      inv[r] = 1.0f / (sqrtf(N) + 1e-8f);
    }
    #pragma unroll
    for (int nt = 0; nt < 8; ++nt)
      #pragma unroll
      for (int r = 0; r < 4; ++r)
        s_amp[(quad * 4 + r) * 516 + w * 128 + nt * 16 + m] = a[nt][r] * inv[r];
    __syncthreads();   // #4: s_amp ready
  } else {
    float p[8][4];
    #pragma unroll
    for (int nt = 0; nt < 8; ++nt)
      #pragma unroll
      for (int r = 0; r < 4; ++r) {
        float e2 = __expf(2.0f * y[nt][r]);
        p[nt][r] = (1.0f - 2.0f * __builtin_amdgcn_rcpf(e2 + 1.0f)) * PI_F;
      }
    __syncthreads();   // #3 (match amp waves)
    __syncthreads();   // #4: s_amp ready
    const double GAM = 1024.0 / 1023.0;   // table-step rescale (linspace endpoint)
    const int hbase = (w - 4) * 2;
    float c1[2], s1g[2];
    #pragma unroll
    for (int hh = 0; hh < 2; ++hh) {
      c1[hh]  = (float)((double)fr[hbase + hh] * GAM);
      s1g[hh] = (float)((double)psh[hbase + hh] * GAM);
    }
    #pragma unroll
    for (int nt = 0; nt < 8; ++nt) {
      const int hh = nt >> 2;
      const int pc = (w - 4) * 128 + nt * 16 + m;
      const int d = pc & 63;
      #pragma unroll
      for (int r = 0; r < 4; ++r) {
        const int i = r0 + quad * 4 + r;
        float af = s_amp[(quad * 4 + r) * 516 + pc];
        float A = fmaf(p[nt][r], c1[hh], s1g[hh]);
        float Bp = p[nt][r] * c1[hh];
        float cA, sA, cB, sB;
        __sincosf(A, &sA, &cA);
        __sincosf(Bp, &sB, &cB);
        size_t base = ((size_t)(hbase + hh) * 2048 + i) * 128 + d;
        Ub[base]      = f2bf(af * cA);
        Ub[base + 64] = f2bf(af * sA);
        Wb[base]      = f2bf(af * cB);
        Wb[base + 64] = f2bf(af * sB);
      }
    }
  }
}

// ------- single-pass MFMA flash, redundancy-free wave mapping ----------------
// 512 thr = 8 waves.  Scores: wave owns 16-k strip of the 128-k tile (4 B-frag
// reads/kt; U A-frags for all 4 q-groups in regs).  PV: wave owns
// (qg = wave&3, dh = wave>>2): O[16q x 32d] over full k; vf preloaded to regs
// before the barrier; every wave computes den redundantly (no LDS exchange).
__global__ __launch_bounds__(512, 1) void k_flash6(const unsigned short* __restrict__ Ub,
    const unsigned short* __restrict__ Wb, const unsigned short* __restrict__ vT,
    unsigned short* __restrict__ attb) {
  __shared__ __align__(16) unsigned char s_w[2][128 * 272];  // [k][f 128 bf16 + pad]
  __shared__ __align__(16) unsigned char s_v[2][64 * 272];   // [d][k 128 bf16 + pad]
  __shared__ __align__(16) unsigned char s_p[2][64 * 272];   // [q][k 128 bf16 + pad]
  const int qt = blockIdx.x, h = blockIdx.y;
  const int q0 = qt * 64;
  const int t = threadIdx.x;
  const int wave = t >> 6, lane = t & 63;
  const int qg = wave & 3, dh = wave >> 2;
  const int m = lane & 15, quad = lane >> 4;
  const int sr = t >> 2, sp = t & 3;      // s_w staging: 128 rows x 4 parts
  const int vr = t >> 3, vp = t & 7;      // s_v staging: 64 rows x 8 parts
  // preload U A-frags for ALL 4 q-groups (k-invariant)
  short8 afr[4][4];
  #pragma unroll
  for (int g = 0; g < 4; ++g) {
    const unsigned short* urow = Ub + ((size_t)h * 2048 + q0 + g * 16 + m) * 128;
    #pragma unroll
    for (int fs = 0; fs < 4; ++fs)
      afr[g][fs] = *(const short8*)(urow + fs * 32 + quad * 8);
  }
  short8 ones;
  #pragma unroll
  for (int j = 0; j < 8; ++j) ones[j] = (short)0x3F80;   // bf16 1.0
  f32x4 oacc[2] = {{0,0,0,0},{0,0,0,0}};
  f32x4 dacc = {0, 0, 0, 0};
  const unsigned short* wgbase = Wb + (size_t)h * 2048 * 128 + (size_t)sr * 128;
  const unsigned short* vgbase = vT + ((size_t)h * 64 + vr) * 2048;
  // prologue: stage kt=0 into buffer 0
  #pragma unroll
  for (int it = 0; it < 4; ++it)
    *(short8*)(s_w[0] + sr * 272 + sp * 64 + it * 16) =
      *(const short8*)(wgbase + sp * 32 + it * 8);
  #pragma unroll
  for (int it = 0; it < 2; ++it)
    *(short8*)(s_v[0] + vr * 272 + vp * 32 + it * 16) =
      *(const short8*)(vgbase + vp * 16 + it * 8);
  __syncthreads();
  for (int kt = 0; kt < 16; ++kt) {
    const int cur = kt & 1;
    // issue next tile's global loads (latency overlaps score MFMAs)
    short8 wst[4], vst[2];
    const bool has = (kt < 15);
    if (has) {
      const unsigned short* wg = wgbase + (size_t)(kt + 1) * 128 * 128;
      #pragma unroll
      for (int it = 0; it < 4; ++it)
        wst[it] = *(const short8*)(wg + sp * 32 + it * 8);
      const unsigned short* vg = vgbase + (kt + 1) * 128;
      #pragma unroll
      for (int it = 0; it < 2; ++it)
        vst[it] = *(const short8*)(vg + vp * 16 + it * 8);
    }
    // scores: S[64q x 16k-strip] per wave; 4 B-frag reads, 16 MFMA
    f32x4 sc[4] = {{0,0,0,0},{0,0,0,0},{0,0,0,0},{0,0,0,0}};
    #pragma unroll
    for (int fs = 0; fs < 4; ++fs) {
      short8 bfr = *(const short8*)(s_w[cur] + (wave * 16 + m) * 272 + fs * 64 + quad * 16);
      #pragma unroll
      for (int g = 0; g < 4; ++g)
        sc[g] = MFMA16(afr[g][fs], bfr, sc[g]);
    }
    // p = exp(S/8) -> s_p[kt&1]  (C-layout: row q = g*16+quad*4+r, col k = wave*16+m)
    #pragma unroll
    for (int g = 0; g < 4; ++g)
      #pragma unroll
      for (int r = 0; r < 4; ++r) {
        float p = __expf(sc[g][r] * 0.125f);
        *(unsigned short*)(s_p[cur] + (g * 16 + quad * 4 + r) * 272 +
                           (wave * 16 + m) * 2) = f2bf(p);
      }
    // preload this kt's V B-frags to regs (before barrier: s_v[cur] is stable)
    short8 vf[4][2];
    #pragma unroll
    for (int k2 = 0; k2 < 4; ++k2)
      #pragma unroll
      for (int dt = 0; dt < 2; ++dt)
        vf[k2][dt] = *(const short8*)(s_v[cur] + (dh * 32 + dt * 16 + m) * 272 +
                                      k2 * 64 + quad * 16);
    // commit staged tile to the other buffer
    if (has) {
      #pragma unroll
      for (int it = 0; it < 4; ++it)
        *(short8*)(s_w[cur ^ 1] + sr * 272 + sp * 64 + it * 16) = wst[it];
      #pragma unroll
      for (int it = 0; it < 2; ++it)
        *(short8*)(s_v[cur ^ 1] + vr * 272 + vp * 32 + it * 16) = vst[it];
    }
    __syncthreads();
    // PV + den: wave (qg,dh) computes O[16q x 32d] for this kt's 128 k
    #pragma unroll
    for (int k2 = 0; k2 < 4; ++k2) {
      short8 pf = *(const short8*)(s_p[cur] + (qg * 16 + m) * 272 + k2 * 64 + quad * 16);
      dacc = MFMA16(pf, ones, dacc);
      #pragma unroll
      for (int dt = 0; dt < 2; ++dt)
        oacc[dt] = MFMA16(pf, vf[k2][dt], oacc[dt]);
    }
  }
  // epilogue: normalize own O-strip, write bf16 attb (no cross-wave combine)
  float invd[4];
  #pragma unroll
  for (int r = 0; r < 4; ++r) invd[r] = 1.0f / dacc[r];
  #pragma unroll
  for (int dt = 0; dt < 2; ++dt)
    #pragma unroll
    for (int r = 0; r < 4; ++r)
      attb[(size_t)(q0 + qg * 16 + quad * 4 + r) * 512 + h * 64 +
           dh * 32 + dt * 16 + m] = f2bf(oacc[dt][r] * invd[r]);
}

// ------- out GEMM: out f32 = attb @ WoT^T + bo ----------------
__global__ __launch_bounds__(256) void k_gemm(const unsigned short* __restrict__ A,
    const unsigned short* __restrict__ Bt, const float* __restrict__ bias,
    float* __restrict__ C, int N) {
  __shared__ __align__(16) unsigned char sm[2 * 64 * 136];
  unsigned char* s_a = sm;
  unsigned char* s_b = sm + 64 * 136;
  const int m0 = blockIdx.x * 64, n0 = blockIdx.y * 64;
  const int t = threadIdx.x;
  const int wave = t >> 6, lane = t & 63;
  const int m = lane & 15, quad = lane >> 4;
  const int sr = t >> 2, spart = t & 3;
  f32x4 acc[4] = {{0,0,0,0},{0,0,0,0},{0,0,0,0},{0,0,0,0}};
  for (int kc = 0; kc < 512; kc += 64) {
    #pragma unroll
    for (int it = 0; it < 2; ++it) {
      *(short8*)(s_a + sr * 136 + spart * 32 + it * 16) =
        *(const short8*)(A + (size_t)(m0 + sr) * 512 + kc + spart * 16 + it * 8);
      *(short8*)(s_b + sr * 136 + spart * 32 + it * 16) =
        *(const short8*)(Bt + (size_t)(n0 + sr) * 512 + kc + spart * 16 + it * 8);
    }
    __syncthreads();
    #pragma unroll
    for (int k2 = 0; k2 < 2; ++k2) {
      short8 af = *(const short8*)(s_a + (wave * 16 + m) * 136 + k2 * 64 + quad * 16);
      #pragma unroll
      for (int nt = 0; nt < 4; ++nt) {
        short8 bf = *(const short8*)(s_b + (nt * 16 + m) * 136 + k2 * 64 + quad * 16);
        acc[nt] = MFMA16(af, bf, acc[nt]);
      }
    }
    __syncthreads();
  }
  #pragma unroll
  for (int nt = 0; nt < 4; ++nt) {
    int col = n0 + nt * 16 + m;
    float bv = bias[col];
    #pragma unroll
    for (int r = 0; r < 4; ++r) {
      int row = m0 + wave * 16 + quad * 4 + r;
      C[(size_t)row * N + col] = acc[nt][r] + bv;
    }
  }
}

extern "C" void kernel_launch(void* const* d_in, const int* in_sizes, int n_in,
                              void* d_out, int out_size, void* d_ws, size_t ws_size,
                              hipStream_t stream) {
  (void)in_sizes; (void)n_in; (void)out_size; (void)ws_size;
  const float* x   = (const float*)d_in[0];
  const float* Wq  = (const float*)d_in[1];
  const float* bq  = (const float*)d_in[2];
  const float* lnw = (const float*)d_in[3];
  const float* lnb = (const float*)d_in[4];
  const float* fr  = (const float*)d_in[5];
  const float* ps  = (const float*)d_in[6];
  const float* Wo  = (const float*)d_in[7];
  const float* bo  = (const float*)d_in[8];
  // d_in[9] = cos_table: unused (smooth-cos factorization)
  char* ws = (char*)d_ws;
  unsigned short* attb = (unsigned short*)(ws + B_ATTB);
  unsigned short* Ub   = (unsigned short*)(ws + B_UB);
  unsigned short* Wb   = (unsigned short*)(ws + B_WB);
  unsigned short* vT   = (unsigned short*)(ws + B_VT);
  unsigned short* WqTp = (unsigned short*)(ws + B_WQT);
  unsigned short* WoT  = (unsigned short*)(ws + B_WOT);
  float* out = (float*)d_out;

  k_prep<<<448, 256, 0, stream>>>(x, Wq, Wo, vT, WqTp, WoT);
  k_qs_ln<<<128, 512, 0, stream>>>(x, WqTp, bq, lnw, lnb, fr, ps, Ub, Wb);
  k_flash6<<<dim3(32, 8), 512, 0, stream>>>(Ub, Wb, vT, attb);
  k_gemm<<<dim3(32, 8), 256, 0, stream>>>(attb, WoT, bo, out, 512);
}